// Round 1
// baseline (53372.699 us; speedup 1.0000x reference)
//
#include <hip/hip_runtime.h>

#define TPB 256
static inline int nblk(long n) { return (int)((n + TPB - 1) / TPB); }

// ---------------- transpose (B,3,V) -> (B,V,3) ----------------
__global__ void transpose_verts(const float* __restrict__ vin, float* __restrict__ verts,
                                int B, int V) {
    int t = blockIdx.x * blockDim.x + threadIdx.x;
    if (t >= B * V) return;
    int b = t / V, i = t % V;
    const float* p = vin + (size_t)b * 3 * V;
    float* o = verts + (size_t)t * 3;
    o[0] = p[i]; o[1] = p[V + i]; o[2] = p[2 * V + i];
}

// ---------------- KNN: K nearest excluding self ----------------
// verts indexed with fixed row-stride 1024 per batch (stage verts are prefixes).
template <int K>
__global__ void knn_kernel(const float* __restrict__ verts, int* __restrict__ knn,
                           int V_full, int V_out) {
    __shared__ float pts[1024 * 3];
    __shared__ float sq[1024];
    int b = blockIdx.y;
    const float* vb = verts + (size_t)b * 1024 * 3;
    for (int j = threadIdx.x; j < V_full; j += blockDim.x) {
        float x = vb[j * 3], y = vb[j * 3 + 1], z = vb[j * 3 + 2];
        pts[j * 3] = x; pts[j * 3 + 1] = y; pts[j * 3 + 2] = z;
        sq[j] = x * x + y * y + z * z;
    }
    __syncthreads();
    int i = blockIdx.x * blockDim.x + threadIdx.x;
    if (i >= V_out) return;
    float px = pts[i * 3], py = pts[i * 3 + 1], pz = pts[i * 3 + 2];
    float sqi = sq[i];
    float bd[K]; int bi[K];
#pragma unroll
    for (int t = 0; t < K; ++t) { bd[t] = 3.402823466e38f; bi[t] = -1; }
    for (int j = 0; j < V_full; ++j) {
        if (j == i) continue;
        float d = sqi + sq[j] - 2.f * (px * pts[j * 3] + py * pts[j * 3 + 1] + pz * pts[j * 3 + 2]);
        if (d < bd[K - 1]) {
            bd[K - 1] = d; bi[K - 1] = j;
#pragma unroll
            for (int t = K - 1; t >= 1; --t) {
                if (bd[t] < bd[t - 1]) {
                    float td = bd[t]; bd[t] = bd[t - 1]; bd[t - 1] = td;
                    int ti = bi[t]; bi[t] = bi[t - 1]; bi[t - 1] = ti;
                }
            }
        }
    }
    int row = b * V_out + i;
#pragma unroll
    for (int t = 0; t < K; ++t) knn[(size_t)row * K + t] = bi[t];
}

// ---------------- normalized neighbor directions ----------------
__global__ void ndir_kernel(const int* __restrict__ knn, const float* __restrict__ verts,
                            float* __restrict__ ndir, int B, int Vst, int K) {
    int t = blockIdx.x * blockDim.x + threadIdx.x;
    if (t >= B * Vst * K) return;
    int row = t / K;
    int b = row / Vst, i = row % Vst;
    int j = knn[t];
    const float* vb = verts + (size_t)b * 1024 * 3;
    float dx = vb[j * 3]     - vb[i * 3];
    float dy = vb[j * 3 + 1] - vb[i * 3 + 1];
    float dz = vb[j * 3 + 2] - vb[i * 3 + 2];
    float nrm = sqrtf(dx * dx + dy * dy + dz * dz);
    float inv = 1.f / fmaxf(nrm, 1e-12f);
    ndir[(size_t)t * 3] = dx * inv;
    ndir[(size_t)t * 3 + 1] = dy * inv;
    ndir[(size_t)t * 3 + 2] = dz * inv;
}

// ---------------- conv_surface: fm0 = max_n relu(ndir . sdir_c) ----------------
__global__ void conv_surface_kernel(const float* __restrict__ ndir, const float* __restrict__ dir,
                                    float* __restrict__ fm0, int rows, int K, int C) {
    int t = blockIdx.x * blockDim.x + threadIdx.x;
    if (t >= rows * C) return;
    int row = t / C, c = t % C;
    float d0 = dir[c], d1 = dir[C + c], d2 = dir[2 * C + c];
    float inv = 1.f / fmaxf(sqrtf(d0 * d0 + d1 * d1 + d2 * d2), 1e-12f);
    d0 *= inv; d1 *= inv; d2 *= inv;
    float m = -3.402823466e38f;
    const float* nd = ndir + (size_t)row * K * 3;
    for (int n = 0; n < K; ++n) {
        float th = fmaxf(nd[n * 3] * d0 + nd[n * 3 + 1] * d1 + nd[n * 3 + 2] * d2, 0.f);
        m = fmaxf(m, th);
    }
    fm0[t] = m; // relu(max of relus) == max
}

// ---------------- GEMM: out[r,c] = in[r,:]@w[:,c] + bias[c]  (w row-major Cin x Cw) ----------------
__global__ void gemm_bias_kernel(const float* __restrict__ in, const float* __restrict__ w,
                                 const float* __restrict__ bias, float* __restrict__ out,
                                 int rows, int Cin, int Cw) {
    int t = blockIdx.x * blockDim.x + threadIdx.x;
    int nc4 = Cw >> 2;
    if (t >= rows * nc4) return;
    int r = t / nc4, c4 = (t % nc4) * 4;
    float4 acc = *(const float4*)(bias + c4);
    const float* inr = in + (size_t)r * Cin;
    for (int k = 0; k < Cin; ++k) {
        float a = inr[k];
        float4 wv = *(const float4*)(w + (size_t)k * Cw + c4);
        acc.x += a * wv.x; acc.y += a * wv.y; acc.z += a * wv.z; acc.w += a * wv.w;
    }
    *(float4*)(out + (size_t)r * Cw + c4) = acc;
}

// ---------------- conv_layer: center + max_n(theta * support) ----------------
__global__ void conv_act_kernel(const float* __restrict__ ndir, const int* __restrict__ knn,
                                const float* __restrict__ fout, const float* __restrict__ dir,
                                float* __restrict__ out, int B, int Vst, int K, int Cout) {
    int t = blockIdx.x * blockDim.x + threadIdx.x;
    if (t >= B * Vst * Cout) return;
    int row = t / Cout, c = t % Cout;
    int b = row / Vst;
    float d0 = dir[c], d1 = dir[Cout + c], d2 = dir[2 * Cout + c];
    float inv = 1.f / fmaxf(sqrtf(d0 * d0 + d1 * d1 + d2 * d2), 1e-12f);
    d0 *= inv; d1 *= inv; d2 *= inv;
    int Cw = 2 * Cout;
    float m = -3.402823466e38f;
    const float* nd = ndir + (size_t)row * K * 3;
    const int* kr = knn + (size_t)row * K;
    for (int n = 0; n < K; ++n) {
        int j = kr[n];
        float th = fmaxf(nd[n * 3] * d0 + nd[n * 3 + 1] * d1 + nd[n * 3 + 2] * d2, 0.f);
        float s = fout[((size_t)(b * Vst + j)) * Cw + Cout + c];
        m = fmaxf(m, th * s);
    }
    out[t] = fout[(size_t)row * Cw + c] + m;
}

// ---------------- BN stats: mean + rsqrt(var+eps) per channel ----------------
__global__ void bn_stats_kernel(const float* __restrict__ x, float* __restrict__ stats,
                                int rows, int C) {
    int c = blockIdx.x;
    double s = 0.0, ss = 0.0;
    for (int r = threadIdx.x; r < rows; r += blockDim.x) {
        float v = x[(size_t)r * C + c];
        s += v; ss += (double)v * v;
    }
    __shared__ double sh[TPB], sh2[TPB];
    sh[threadIdx.x] = s; sh2[threadIdx.x] = ss;
    __syncthreads();
    for (int off = TPB / 2; off > 0; off >>= 1) {
        if (threadIdx.x < off) { sh[threadIdx.x] += sh[threadIdx.x + off]; sh2[threadIdx.x] += sh2[threadIdx.x + off]; }
        __syncthreads();
    }
    if (threadIdx.x == 0) {
        double m = sh[0] / rows;
        double var = sh2[0] / rows - m * m;
        if (var < 0) var = 0;
        stats[c] = (float)m;
        stats[C + c] = rsqrtf((float)var + 1e-5f);
    }
}

// ---------------- BN apply + relu + fused residual (fm_in @ dw^T) ----------------
__global__ void bn_apply_res_kernel(const float* __restrict__ conv, const float* __restrict__ stats,
                                    const float* __restrict__ fmin, const float* __restrict__ dw,
                                    float* __restrict__ out, int rows, int C, int Cin) {
    int t = blockIdx.x * blockDim.x + threadIdx.x;
    if (t >= rows * C) return;
    int row = t / C, c = t % C;
    float v = fmaxf((conv[t] - stats[c]) * stats[C + c], 0.f);
    const float4* a = (const float4*)(fmin + (size_t)row * Cin);
    const float4* wr = (const float4*)(dw + (size_t)c * Cin);
    float acc = 0.f;
    int n4 = Cin >> 2;
    for (int k = 0; k < n4; ++k) {
        float4 av = a[k], wv = wr[k];
        acc += av.x * wv.x + av.y * wv.y + av.z * wv.z + av.w * wv.w;
    }
    out[t] = v + acc;
}

// ---------------- pool: max over 4 NN features, first pn rows ----------------
__global__ void pool_max_kernel(const float* __restrict__ fm, const int* __restrict__ knn4,
                                float* __restrict__ out, int B, int Vin, int pn, int C) {
    int t = blockIdx.x * blockDim.x + threadIdx.x;
    if (t >= B * pn * C) return;
    int row = t / C, c = t % C;
    int b = row / pn;
    const int* kr = knn4 + (size_t)row * 4;
    float m = -3.402823466e38f;
    for (int n = 0; n < 4; ++n) {
        int j = kr[n];
        m = fmaxf(m, fm[((size_t)(b * Vin + j)) * C + c]);
    }
    out[t] = m;
}

// ---------------- g = max over vertices ----------------
__global__ void rowmax_kernel(const float* __restrict__ fm, float* __restrict__ g,
                              int B, int V, int C) {
    int t = blockIdx.x * blockDim.x + threadIdx.x;
    if (t >= B * C) return;
    int b = t / C, c = t % C;
    float m = -3.402823466e38f;
    for (int i = 0; i < V; ++i) m = fmaxf(m, fm[((size_t)(b * V + i)) * C + c]);
    g[t] = m;
}

// ---------------- out[r,c] = in[r,:]@w[c,:] + bias[c]  (w row-major Cout x Cin) ----------------
__global__ void gemm_t_bias_kernel(const float* __restrict__ in, const float* __restrict__ w,
                                   const float* __restrict__ bias, float* __restrict__ out,
                                   int rows, int Cin, int Cout) {
    int t = blockIdx.x * blockDim.x + threadIdx.x;
    if (t >= rows * Cout) return;
    int r = t / Cout, c = t % Cout;
    const float4* a = (const float4*)(in + (size_t)r * Cin);
    const float4* wr = (const float4*)(w + (size_t)c * Cin);
    float acc = 0.f;
    int n4 = Cin >> 2;
    for (int k = 0; k < n4; ++k) {
        float4 av = a[k], wv = wr[k];
        acc += av.x * wv.x + av.y * wv.y + av.z * wv.z + av.w * wv.w;
    }
    out[t] = acc + bias[c];
}

// ---------------- classifier BN stats over batch (32) ----------------
__global__ void cls_bn_stats_kernel(const float* __restrict__ h, float* __restrict__ stats) {
    int c = blockIdx.x * blockDim.x + threadIdx.x;
    if (c >= 256) return;
    float s = 0.f, ss = 0.f;
    for (int b = 0; b < 32; ++b) {
        float v = h[(size_t)b * 256 + c];
        s += v; ss += v * v;
    }
    float m = s / 32.f;
    float var = ss / 32.f - m * m;
    if (var < 0.f) var = 0.f;
    stats[c] = m;
    stats[256 + c] = rsqrtf(var + 1e-5f);
}

// ---------------- final: relu(bn(h)*g+beta) @ w2^T + b2 ----------------
__global__ void cls_final_kernel(const float* __restrict__ h, const float* __restrict__ stats,
                                 const float* __restrict__ gam, const float* __restrict__ beta,
                                 const float* __restrict__ w2, const float* __restrict__ b2,
                                 float* __restrict__ out) {
    int t = blockIdx.x * blockDim.x + threadIdx.x;
    if (t >= 32 * 40) return;
    int b = t / 40, o = t % 40;
    float acc = b2[o];
    for (int c = 0; c < 256; ++c) {
        float v = fmaxf((h[(size_t)b * 256 + c] - stats[c]) * stats[256 + c] * gam[c] + beta[c], 0.f);
        acc += v * w2[(size_t)o * 256 + c];
    }
    out[t] = acc;
}

extern "C" void kernel_launch(void* const* d_in, const int* in_sizes, int n_in,
                              void* d_out, int out_size, void* d_ws, size_t ws_size,
                              hipStream_t stream) {
    const float* vertices = (const float*)d_in[0];
    const float* c0_dir = (const float*)d_in[1];
    const float* c1_w  = (const float*)d_in[2];
    const float* c1_b  = (const float*)d_in[3];
    const float* c1_dir = (const float*)d_in[4];
    const float* d1_w  = (const float*)d_in[5];
    const float* c2_w  = (const float*)d_in[6];
    const float* c2_b  = (const float*)d_in[7];
    const float* c2_dir = (const float*)d_in[8];
    const float* d2_w  = (const float*)d_in[9];
    const float* c3_w  = (const float*)d_in[10];
    const float* c3_b  = (const float*)d_in[11];
    const float* c3_dir = (const float*)d_in[12];
    const float* d3_w  = (const float*)d_in[13];
    const float* c4_w  = (const float*)d_in[14];
    const float* c4_b  = (const float*)d_in[15];
    const float* c4_dir = (const float*)d_in[16];
    const float* d4_w  = (const float*)d_in[17];
    const float* cls_w1 = (const float*)d_in[18];
    const float* cls_b1 = (const float*)d_in[19];
    const float* cls_g  = (const float*)d_in[20];
    const float* cls_beta = (const float*)d_in[21];
    const float* cls_w2 = (const float*)d_in[22];
    const float* cls_b2 = (const float*)d_in[23];

    const int B = 32;
    float* ws = (float*)d_ws;
    size_t off = 0;
    auto alloc = [&](size_t n) { float* p = ws + off; off += n; return p; };
    float* verts = alloc(98304);            // B*1024*3
    int*   knn   = (int*)alloc(655360);     // max B*1024*20
    float* ndir  = alloc(1966080);          // max B*1024*20*3
    float* fm0   = alloc(1048576);          // B*1024*32
    float* fm1   = alloc(2097152);          // B*1024*64
    float* fm1p  = alloc(524288);           // B*256*64
    float* fm2   = alloc(1048576);          // B*256*128
    float* fm3   = alloc(2097152);          // B*256*256
    float* fm3p  = alloc(524288);           // B*64*256
    float* fm4   = alloc(2097152);          // B*64*1024
    float* fout  = alloc(4194304);          // max B*1024*128 / B*256*512 / B*64*2048
    float* convp = alloc(2097152);          // pre-BN conv out (max B*1024*64 / B*64*1024)
    float* stats = alloc(2048);             // mean + inv, max C=1024
    float* gbuf  = alloc(32768);            // B*1024
    float* hbuf  = alloc(8192);             // B*256
    float* hstats = alloc(512);

    // ---- stage 1 (V=1024) ----
    transpose_verts<<<nblk(B * 1024), TPB, 0, stream>>>(vertices, verts, B, 1024);
    knn_kernel<20><<<dim3(4, B), TPB, 0, stream>>>(verts, knn, 1024, 1024);
    ndir_kernel<<<nblk((long)B * 1024 * 20), TPB, 0, stream>>>(knn, verts, ndir, B, 1024, 20);
    conv_surface_kernel<<<nblk((long)B * 1024 * 32), TPB, 0, stream>>>(ndir, c0_dir, fm0, B * 1024, 20, 32);
    gemm_bias_kernel<<<nblk((long)B * 1024 * 32), TPB, 0, stream>>>(fm0, c1_w, c1_b, fout, B * 1024, 32, 128);
    conv_act_kernel<<<nblk((long)B * 1024 * 64), TPB, 0, stream>>>(ndir, knn, fout, c1_dir, convp, B, 1024, 20, 64);
    bn_stats_kernel<<<64, TPB, 0, stream>>>(convp, stats, B * 1024, 64);
    bn_apply_res_kernel<<<nblk((long)B * 1024 * 64), TPB, 0, stream>>>(convp, stats, fm0, d1_w, fm1, B * 1024, 64, 32);
    // pool 1024 -> 256
    knn_kernel<4><<<dim3(1, B), TPB, 0, stream>>>(verts, knn, 1024, 256);
    pool_max_kernel<<<nblk((long)B * 256 * 64), TPB, 0, stream>>>(fm1, knn, fm1p, B, 1024, 256, 64);

    // ---- stage 2 (V=256) ----
    knn_kernel<20><<<dim3(1, B), TPB, 0, stream>>>(verts, knn, 256, 256);
    ndir_kernel<<<nblk((long)B * 256 * 20), TPB, 0, stream>>>(knn, verts, ndir, B, 256, 20);
    gemm_bias_kernel<<<nblk((long)B * 256 * 64), TPB, 0, stream>>>(fm1p, c2_w, c2_b, fout, B * 256, 64, 256);
    conv_act_kernel<<<nblk((long)B * 256 * 128), TPB, 0, stream>>>(ndir, knn, fout, c2_dir, convp, B, 256, 20, 128);
    bn_stats_kernel<<<128, TPB, 0, stream>>>(convp, stats, B * 256, 128);
    bn_apply_res_kernel<<<nblk((long)B * 256 * 128), TPB, 0, stream>>>(convp, stats, fm1p, d2_w, fm2, B * 256, 128, 64);
    gemm_bias_kernel<<<nblk((long)B * 256 * 128), TPB, 0, stream>>>(fm2, c3_w, c3_b, fout, B * 256, 128, 512);
    conv_act_kernel<<<nblk((long)B * 256 * 256), TPB, 0, stream>>>(ndir, knn, fout, c3_dir, convp, B, 256, 20, 256);
    bn_stats_kernel<<<256, TPB, 0, stream>>>(convp, stats, B * 256, 256);
    bn_apply_res_kernel<<<nblk((long)B * 256 * 256), TPB, 0, stream>>>(convp, stats, fm2, d3_w, fm3, B * 256, 256, 128);
    // pool 256 -> 64
    knn_kernel<4><<<dim3(1, B), TPB, 0, stream>>>(verts, knn, 256, 64);
    pool_max_kernel<<<nblk((long)B * 64 * 256), TPB, 0, stream>>>(fm3, knn, fm3p, B, 256, 64, 256);

    // ---- stage 3 (V=64) ----
    knn_kernel<20><<<dim3(1, B), TPB, 0, stream>>>(verts, knn, 64, 64);
    ndir_kernel<<<nblk((long)B * 64 * 20), TPB, 0, stream>>>(knn, verts, ndir, B, 64, 20);
    gemm_bias_kernel<<<nblk((long)B * 64 * 512), TPB, 0, stream>>>(fm3p, c4_w, c4_b, fout, B * 64, 256, 2048);
    conv_act_kernel<<<nblk((long)B * 64 * 1024), TPB, 0, stream>>>(ndir, knn, fout, c4_dir, convp, B, 64, 20, 1024);
    bn_stats_kernel<<<1024, TPB, 0, stream>>>(convp, stats, B * 64, 1024);
    bn_apply_res_kernel<<<nblk((long)B * 64 * 1024), TPB, 0, stream>>>(convp, stats, fm3p, d4_w, fm4, B * 64, 1024, 256);

    // ---- classifier ----
    rowmax_kernel<<<nblk((long)B * 1024), TPB, 0, stream>>>(fm4, gbuf, B, 64, 1024);
    gemm_t_bias_kernel<<<nblk((long)B * 256), TPB, 0, stream>>>(gbuf, cls_w1, cls_b1, hbuf, B, 1024, 256);
    cls_bn_stats_kernel<<<1, TPB, 0, stream>>>(hbuf, hstats);
    cls_final_kernel<<<nblk(32 * 40), TPB, 0, stream>>>(hbuf, hstats, cls_g, cls_beta, cls_w2, cls_b2, (float*)d_out);
}

// Round 4
// 2509.316 us; speedup vs baseline: 21.2698x; 21.2698x over previous
//
#include <hip/hip_runtime.h>

#define TPB 256
static inline int nblk(long n) { return (int)((n + TPB - 1) / TPB); }

// ---------------- transpose (B,3,V) -> (B,V,3) ----------------
__global__ __launch_bounds__(TPB) void transpose_verts(const float* __restrict__ vin, float* __restrict__ verts,
                                int B, int V) {
    int t = blockIdx.x * blockDim.x + threadIdx.x;
    if (t >= B * V) return;
    int b = t / V, i = t % V;
    const float* p = vin + (size_t)b * 3 * V;
    float* o = verts + (size_t)t * 3;
    o[0] = p[i]; o[1] = p[V + i]; o[2] = p[2 * V + i];
}

// ---------------- KNN: K nearest excluding self ----------------
// verts indexed with fixed row-stride 1024 per batch (stage verts are prefixes).
// __launch_bounds__(TPB,1): allow up to 512 VGPRs so the top-K arrays stay in
// registers (without it the compiler caps at 64 VGPRs and spills -> 39 GB scratch).
template <int K>
__global__ __launch_bounds__(TPB, 1) void knn_kernel(const float* __restrict__ verts, int* __restrict__ knn,
                           int V_full, int V_out) {
    __shared__ float4 pts[1024]; // (x, y, z, |p|^2)
    int b = blockIdx.y;
    const float* vb = verts + (size_t)b * 1024 * 3;
    for (int j = threadIdx.x; j < V_full; j += blockDim.x) {
        float x = vb[j * 3], y = vb[j * 3 + 1], z = vb[j * 3 + 2];
        pts[j] = make_float4(x, y, z, x * x + y * y + z * z);
    }
    __syncthreads();
    int i = blockIdx.x * blockDim.x + threadIdx.x;
    if (i >= V_out) return;
    float4 pi = pts[i];
    float px = pi.x, py = pi.y, pz = pi.z, sqi = pi.w;
    float bd[K]; int bi[K];
#pragma unroll
    for (int t = 0; t < K; ++t) { bd[t] = 3.402823466e38f; bi[t] = -1; }
    for (int j = 0; j < V_full; ++j) {
        float4 pj = pts[j];
        float d = sqi + pj.w - 2.f * (px * pj.x + py * pj.y + pz * pj.z);
        d = (j == i) ? 3.402823466e38f : d; // branchless self-exclusion
        if (d < bd[K - 1]) {
            bd[K - 1] = d; bi[K - 1] = j;
#pragma unroll
            for (int t = K - 1; t >= 1; --t) {
                if (bd[t] < bd[t - 1]) {
                    float td = bd[t]; bd[t] = bd[t - 1]; bd[t - 1] = td;
                    int ti = bi[t]; bi[t] = bi[t - 1]; bi[t - 1] = ti;
                }
            }
        }
    }
    int row = b * V_out + i;
#pragma unroll
    for (int t = 0; t < K; ++t) knn[(size_t)row * K + t] = bi[t];
}

// ---------------- normalized neighbor directions ----------------
__global__ __launch_bounds__(TPB) void ndir_kernel(const int* __restrict__ knn, const float* __restrict__ verts,
                            float* __restrict__ ndir, int B, int Vst, int K) {
    int t = blockIdx.x * blockDim.x + threadIdx.x;
    if (t >= B * Vst * K) return;
    int row = t / K;
    int b = row / Vst, i = row % Vst;
    int j = knn[t];
    const float* vb = verts + (size_t)b * 1024 * 3;
    float dx = vb[j * 3]     - vb[i * 3];
    float dy = vb[j * 3 + 1] - vb[i * 3 + 1];
    float dz = vb[j * 3 + 2] - vb[i * 3 + 2];
    float nrm = sqrtf(dx * dx + dy * dy + dz * dz);
    float inv = 1.f / fmaxf(nrm, 1e-12f);
    ndir[(size_t)t * 3] = dx * inv;
    ndir[(size_t)t * 3 + 1] = dy * inv;
    ndir[(size_t)t * 3 + 2] = dz * inv;
}

// ---------------- conv_surface: fm0 = max_n relu(ndir . sdir_c) ----------------
__global__ __launch_bounds__(TPB) void conv_surface_kernel(const float* __restrict__ ndir, const float* __restrict__ dir,
                                    float* __restrict__ fm0, int rows, int K, int C) {
    int t = blockIdx.x * blockDim.x + threadIdx.x;
    if (t >= rows * C) return;
    int row = t / C, c = t % C;
    float d0 = dir[c], d1 = dir[C + c], d2 = dir[2 * C + c];
    float inv = 1.f / fmaxf(sqrtf(d0 * d0 + d1 * d1 + d2 * d2), 1e-12f);
    d0 *= inv; d1 *= inv; d2 *= inv;
    float m = -3.402823466e38f;
    const float* nd = ndir + (size_t)row * K * 3;
    for (int n = 0; n < K; ++n) {
        float th = fmaxf(nd[n * 3] * d0 + nd[n * 3 + 1] * d1 + nd[n * 3 + 2] * d2, 0.f);
        m = fmaxf(m, th);
    }
    fm0[t] = m; // relu(max of relus) == max
}

// ---------------- GEMM: out[r,c] = in[r,:]@w[:,c] + bias[c]  (w row-major Cin x Cw) ----------------
__global__ __launch_bounds__(TPB) void gemm_bias_kernel(const float* __restrict__ in, const float* __restrict__ w,
                                 const float* __restrict__ bias, float* __restrict__ out,
                                 int rows, int Cin, int Cw) {
    int t = blockIdx.x * blockDim.x + threadIdx.x;
    int nc4 = Cw >> 2;
    if (t >= rows * nc4) return;
    int r = t / nc4, c4 = (t % nc4) * 4;
    float4 acc = *(const float4*)(bias + c4);
    const float* inr = in + (size_t)r * Cin;
    for (int k = 0; k < Cin; ++k) {
        float a = inr[k];
        float4 wv = *(const float4*)(w + (size_t)k * Cw + c4);
        acc.x += a * wv.x; acc.y += a * wv.y; acc.z += a * wv.z; acc.w += a * wv.w;
    }
    *(float4*)(out + (size_t)r * Cw + c4) = acc;
}

// ---------------- conv_layer: center + max_n(theta * support) ----------------
__global__ __launch_bounds__(TPB) void conv_act_kernel(const float* __restrict__ ndir, const int* __restrict__ knn,
                                const float* __restrict__ fout, const float* __restrict__ dir,
                                float* __restrict__ out, int B, int Vst, int K, int Cout) {
    int t = blockIdx.x * blockDim.x + threadIdx.x;
    if (t >= B * Vst * Cout) return;
    int row = t / Cout, c = t % Cout;
    int b = row / Vst;
    float d0 = dir[c], d1 = dir[Cout + c], d2 = dir[2 * Cout + c];
    float inv = 1.f / fmaxf(sqrtf(d0 * d0 + d1 * d1 + d2 * d2), 1e-12f);
    d0 *= inv; d1 *= inv; d2 *= inv;
    int Cw = 2 * Cout;
    float m = -3.402823466e38f;
    const float* nd = ndir + (size_t)row * K * 3;
    const int* kr = knn + (size_t)row * K;
    for (int n = 0; n < K; ++n) {
        int j = kr[n];
        float th = fmaxf(nd[n * 3] * d0 + nd[n * 3 + 1] * d1 + nd[n * 3 + 2] * d2, 0.f);
        float s = fout[((size_t)(b * Vst + j)) * Cw + Cout + c];
        m = fmaxf(m, th * s);
    }
    out[t] = fout[(size_t)row * Cw + c] + m;
}

// ---------------- BN stats: mean + rsqrt(var+eps) per channel ----------------
__global__ __launch_bounds__(TPB) void bn_stats_kernel(const float* __restrict__ x, float* __restrict__ stats,
                                int rows, int C) {
    int c = blockIdx.x;
    double s = 0.0, ss = 0.0;
    for (int r = threadIdx.x; r < rows; r += blockDim.x) {
        float v = x[(size_t)r * C + c];
        s += v; ss += (double)v * v;
    }
    __shared__ double sh[TPB], sh2[TPB];
    sh[threadIdx.x] = s; sh2[threadIdx.x] = ss;
    __syncthreads();
    for (int off = TPB / 2; off > 0; off >>= 1) {
        if (threadIdx.x < off) { sh[threadIdx.x] += sh[threadIdx.x + off]; sh2[threadIdx.x] += sh2[threadIdx.x + off]; }
        __syncthreads();
    }
    if (threadIdx.x == 0) {
        double m = sh[0] / rows;
        double var = sh2[0] / rows - m * m;
        if (var < 0) var = 0;
        stats[c] = (float)m;
        stats[C + c] = rsqrtf((float)var + 1e-5f);
    }
}

// ---------------- BN apply + relu + fused residual (fm_in @ dw^T) ----------------
__global__ __launch_bounds__(TPB) void bn_apply_res_kernel(const float* __restrict__ conv, const float* __restrict__ stats,
                                    const float* __restrict__ fmin, const float* __restrict__ dw,
                                    float* __restrict__ out, int rows, int C, int Cin) {
    int t = blockIdx.x * blockDim.x + threadIdx.x;
    if (t >= rows * C) return;
    int row = t / C, c = t % C;
    float v = fmaxf((conv[t] - stats[c]) * stats[C + c], 0.f);
    const float4* a = (const float4*)(fmin + (size_t)row * Cin);
    const float4* wr = (const float4*)(dw + (size_t)c * Cin);
    float acc = 0.f;
    int n4 = Cin >> 2;
    for (int k = 0; k < n4; ++k) {
        float4 av = a[k], wv = wr[k];
        acc += av.x * wv.x + av.y * wv.y + av.z * wv.z + av.w * wv.w;
    }
    out[t] = v + acc;
}

// ---------------- pool: max over 4 NN features, first pn rows ----------------
__global__ __launch_bounds__(TPB) void pool_max_kernel(const float* __restrict__ fm, const int* __restrict__ knn4,
                                float* __restrict__ out, int B, int Vin, int pn, int C) {
    int t = blockIdx.x * blockDim.x + threadIdx.x;
    if (t >= B * pn * C) return;
    int row = t / C, c = t % C;
    int b = row / pn;
    const int* kr = knn4 + (size_t)row * 4;
    float m = -3.402823466e38f;
    for (int n = 0; n < 4; ++n) {
        int j = kr[n];
        m = fmaxf(m, fm[((size_t)(b * Vin + j)) * C + c]);
    }
    out[t] = m;
}

// ---------------- g = max over vertices ----------------
__global__ __launch_bounds__(TPB) void rowmax_kernel(const float* __restrict__ fm, float* __restrict__ g,
                              int B, int V, int C) {
    int t = blockIdx.x * blockDim.x + threadIdx.x;
    if (t >= B * C) return;
    int b = t / C, c = t % C;
    float m = -3.402823466e38f;
    for (int i = 0; i < V; ++i) m = fmaxf(m, fm[((size_t)(b * V + i)) * C + c]);
    g[t] = m;
}

// ---------------- out[r,c] = in[r,:]@w[c,:] + bias[c]  (w row-major Cout x Cin) ----------------
__global__ __launch_bounds__(TPB) void gemm_t_bias_kernel(const float* __restrict__ in, const float* __restrict__ w,
                                   const float* __restrict__ bias, float* __restrict__ out,
                                   int rows, int Cin, int Cout) {
    int t = blockIdx.x * blockDim.x + threadIdx.x;
    if (t >= rows * Cout) return;
    int r = t / Cout, c = t % Cout;
    const float4* a = (const float4*)(in + (size_t)r * Cin);
    const float4* wr = (const float4*)(w + (size_t)c * Cin);
    float acc = 0.f;
    int n4 = Cin >> 2;
    for (int k = 0; k < n4; ++k) {
        float4 av = a[k], wv = wr[k];
        acc += av.x * wv.x + av.y * wv.y + av.z * wv.z + av.w * wv.w;
    }
    out[t] = acc + bias[c];
}

// ---------------- classifier BN stats over batch (32) ----------------
__global__ __launch_bounds__(TPB) void cls_bn_stats_kernel(const float* __restrict__ h, float* __restrict__ stats) {
    int c = blockIdx.x * blockDim.x + threadIdx.x;
    if (c >= 256) return;
    float s = 0.f, ss = 0.f;
    for (int b = 0; b < 32; ++b) {
        float v = h[(size_t)b * 256 + c];
        s += v; ss += v * v;
    }
    float m = s / 32.f;
    float var = ss / 32.f - m * m;
    if (var < 0.f) var = 0.f;
    stats[c] = m;
    stats[256 + c] = rsqrtf(var + 1e-5f);
}

// ---------------- final: relu(bn(h)*g+beta) @ w2^T + b2 ----------------
__global__ __launch_bounds__(TPB) void cls_final_kernel(const float* __restrict__ h, const float* __restrict__ stats,
                                 const float* __restrict__ gam, const float* __restrict__ beta,
                                 const float* __restrict__ w2, const float* __restrict__ b2,
                                 float* __restrict__ out) {
    int t = blockIdx.x * blockDim.x + threadIdx.x;
    if (t >= 32 * 40) return;
    int b = t / 40, o = t % 40;
    float acc = b2[o];
    for (int c = 0; c < 256; ++c) {
        float v = fmaxf((h[(size_t)b * 256 + c] - stats[c]) * stats[256 + c] * gam[c] + beta[c], 0.f);
        acc += v * w2[(size_t)o * 256 + c];
    }
    out[t] = acc;
}

extern "C" void kernel_launch(void* const* d_in, const int* in_sizes, int n_in,
                              void* d_out, int out_size, void* d_ws, size_t ws_size,
                              hipStream_t stream) {
    const float* vertices = (const float*)d_in[0];
    const float* c0_dir = (const float*)d_in[1];
    const float* c1_w  = (const float*)d_in[2];
    const float* c1_b  = (const float*)d_in[3];
    const float* c1_dir = (const float*)d_in[4];
    const float* d1_w  = (const float*)d_in[5];
    const float* c2_w  = (const float*)d_in[6];
    const float* c2_b  = (const float*)d_in[7];
    const float* c2_dir = (const float*)d_in[8];
    const float* d2_w  = (const float*)d_in[9];
    const float* c3_w  = (const float*)d_in[10];
    const float* c3_b  = (const float*)d_in[11];
    const float* c3_dir = (const float*)d_in[12];
    const float* d3_w  = (const float*)d_in[13];
    const float* c4_w  = (const float*)d_in[14];
    const float* c4_b  = (const float*)d_in[15];
    const float* c4_dir = (const float*)d_in[16];
    const float* d4_w  = (const float*)d_in[17];
    const float* cls_w1 = (const float*)d_in[18];
    const float* cls_b1 = (const float*)d_in[19];
    const float* cls_g  = (const float*)d_in[20];
    const float* cls_beta = (const float*)d_in[21];
    const float* cls_w2 = (const float*)d_in[22];
    const float* cls_b2 = (const float*)d_in[23];

    const int B = 32;
    float* ws = (float*)d_ws;
    size_t off = 0;
    auto alloc = [&](size_t n) { float* p = ws + off; off += n; return p; };
    float* verts = alloc(98304);            // B*1024*3
    int*   knn   = (int*)alloc(655360);     // max B*1024*20
    float* ndir  = alloc(1966080);          // max B*1024*20*3
    float* fm0   = alloc(1048576);          // B*1024*32
    float* fm1   = alloc(2097152);          // B*1024*64
    float* fm1p  = alloc(524288);           // B*256*64
    float* fm2   = alloc(1048576);          // B*256*128
    float* fm3   = alloc(2097152);          // B*256*256
    float* fm3p  = alloc(524288);           // B*64*256
    float* fm4   = alloc(2097152);          // B*64*1024
    float* fout  = alloc(4194304);          // max B*1024*128 / B*256*512 / B*64*2048
    float* convp = alloc(2097152);          // pre-BN conv out (max B*1024*64 / B*64*1024)
    float* stats = alloc(2048);             // mean + inv, max C=1024
    float* gbuf  = alloc(32768);            // B*1024
    float* hbuf  = alloc(8192);             // B*256
    float* hstats = alloc(512);

    // ---- stage 1 (V=1024) ----
    transpose_verts<<<nblk(B * 1024), TPB, 0, stream>>>(vertices, verts, B, 1024);
    knn_kernel<20><<<dim3(4, B), TPB, 0, stream>>>(verts, knn, 1024, 1024);
    ndir_kernel<<<nblk((long)B * 1024 * 20), TPB, 0, stream>>>(knn, verts, ndir, B, 1024, 20);
    conv_surface_kernel<<<nblk((long)B * 1024 * 32), TPB, 0, stream>>>(ndir, c0_dir, fm0, B * 1024, 20, 32);
    gemm_bias_kernel<<<nblk((long)B * 1024 * 32), TPB, 0, stream>>>(fm0, c1_w, c1_b, fout, B * 1024, 32, 128);
    conv_act_kernel<<<nblk((long)B * 1024 * 64), TPB, 0, stream>>>(ndir, knn, fout, c1_dir, convp, B, 1024, 20, 64);
    bn_stats_kernel<<<64, TPB, 0, stream>>>(convp, stats, B * 1024, 64);
    bn_apply_res_kernel<<<nblk((long)B * 1024 * 64), TPB, 0, stream>>>(convp, stats, fm0, d1_w, fm1, B * 1024, 64, 32);
    // pool 1024 -> 256
    knn_kernel<4><<<dim3(1, B), TPB, 0, stream>>>(verts, knn, 1024, 256);
    pool_max_kernel<<<nblk((long)B * 256 * 64), TPB, 0, stream>>>(fm1, knn, fm1p, B, 1024, 256, 64);

    // ---- stage 2 (V=256) ----
    knn_kernel<20><<<dim3(1, B), TPB, 0, stream>>>(verts, knn, 256, 256);
    ndir_kernel<<<nblk((long)B * 256 * 20), TPB, 0, stream>>>(knn, verts, ndir, B, 256, 20);
    gemm_bias_kernel<<<nblk((long)B * 256 * 64), TPB, 0, stream>>>(fm1p, c2_w, c2_b, fout, B * 256, 64, 256);
    conv_act_kernel<<<nblk((long)B * 256 * 128), TPB, 0, stream>>>(ndir, knn, fout, c2_dir, convp, B, 256, 20, 128);
    bn_stats_kernel<<<128, TPB, 0, stream>>>(convp, stats, B * 256, 128);
    bn_apply_res_kernel<<<nblk((long)B * 256 * 128), TPB, 0, stream>>>(convp, stats, fm1p, d2_w, fm2, B * 256, 128, 64);
    gemm_bias_kernel<<<nblk((long)B * 256 * 128), TPB, 0, stream>>>(fm2, c3_w, c3_b, fout, B * 256, 128, 512);
    conv_act_kernel<<<nblk((long)B * 256 * 256), TPB, 0, stream>>>(ndir, knn, fout, c3_dir, convp, B, 256, 20, 256);
    bn_stats_kernel<<<256, TPB, 0, stream>>>(convp, stats, B * 256, 256);
    bn_apply_res_kernel<<<nblk((long)B * 256 * 256), TPB, 0, stream>>>(convp, stats, fm2, d3_w, fm3, B * 256, 256, 128);
    // pool 256 -> 64
    knn_kernel<4><<<dim3(1, B), TPB, 0, stream>>>(verts, knn, 256, 64);
    pool_max_kernel<<<nblk((long)B * 64 * 256), TPB, 0, stream>>>(fm3, knn, fm3p, B, 256, 64, 256);

    // ---- stage 3 (V=64) ----
    knn_kernel<20><<<dim3(1, B), TPB, 0, stream>>>(verts, knn, 64, 64);
    ndir_kernel<<<nblk((long)B * 64 * 20), TPB, 0, stream>>>(knn, verts, ndir, B, 64, 20);
    gemm_bias_kernel<<<nblk((long)B * 64 * 512), TPB, 0, stream>>>(fm3p, c4_w, c4_b, fout, B * 64, 256, 2048);
    conv_act_kernel<<<nblk((long)B * 64 * 1024), TPB, 0, stream>>>(ndir, knn, fout, c4_dir, convp, B, 64, 20, 1024);
    bn_stats_kernel<<<1024, TPB, 0, stream>>>(convp, stats, B * 64, 1024);
    bn_apply_res_kernel<<<nblk((long)B * 64 * 1024), TPB, 0, stream>>>(convp, stats, fm3p, d4_w, fm4, B * 64, 1024, 256);

    // ---- classifier ----
    rowmax_kernel<<<nblk((long)B * 1024), TPB, 0, stream>>>(fm4, gbuf, B, 64, 1024);
    gemm_t_bias_kernel<<<nblk((long)B * 256), TPB, 0, stream>>>(gbuf, cls_w1, cls_b1, hbuf, B, 1024, 256);
    cls_bn_stats_kernel<<<1, TPB, 0, stream>>>(hbuf, hstats);
    cls_final_kernel<<<nblk(32 * 40), TPB, 0, stream>>>(hbuf, hstats, cls_g, cls_beta, cls_w2, cls_b2, (float*)d_out);
}

// Round 5
// 913.506 us; speedup vs baseline: 58.4262x; 2.7469x over previous
//
#include <hip/hip_runtime.h>

#define TPB 256
static inline int nblk(long n) { return (int)((n + TPB - 1) / TPB); }

#define FINF 3.402823466e38f

// ---------------- transpose (B,3,V) -> (B,V,3) ----------------
__global__ __launch_bounds__(TPB) void transpose_verts(const float* __restrict__ vin, float* __restrict__ verts,
                                int B, int V) {
    int t = blockIdx.x * blockDim.x + threadIdx.x;
    if (t >= B * V) return;
    int b = t / V, i = t % V;
    const float* p = vin + (size_t)b * 3 * V;
    float* o = verts + (size_t)t * 3;
    o[0] = p[i]; o[1] = p[V + i]; o[2] = p[2 * V + i];
}

// ---------------- generic small-matrix transpose: in R x Ccol -> out Ccol x R ----------------
__global__ __launch_bounds__(TPB) void transpose_mat_kernel(const float* __restrict__ in, float* __restrict__ out,
                                                            int R, int Ccol) {
    int t = blockIdx.x * blockDim.x + threadIdx.x;
    if (t >= R * Ccol) return;
    int r = t / Ccol, c = t % Ccol;
    out[(size_t)c * R + r] = in[t];
}

// ---------------- KNN: wave-per-vertex, K nearest excluding self ----------------
// One 64-lane wave per query vertex. Each lane holds NS = V_full/64 candidate
// distances in registers (static indices only). K rounds of wave-wide argmin
// via shfl_xor butterfly (tie-break: lower index, matching jax top_k).
template <int K, int NS>
__global__ __launch_bounds__(TPB, 1) void knn_wave_kernel(const float* __restrict__ verts,
                                                          int* __restrict__ knn, int V_out) {
    constexpr int VF = NS * 64;
    __shared__ float4 pts[VF]; // (x, y, z, |p|^2)
    int b = blockIdx.y;
    const float* vb = verts + (size_t)b * 1024 * 3;
    for (int j = threadIdx.x; j < VF; j += blockDim.x) {
        float x = vb[j * 3], y = vb[j * 3 + 1], z = vb[j * 3 + 2];
        pts[j] = make_float4(x, y, z, x * x + y * y + z * z);
    }
    __syncthreads();
    int lane = threadIdx.x & 63;
    int i = blockIdx.x * 4 + (threadIdx.x >> 6); // 4 waves per block -> 4 vertices
    if (i >= V_out) return;
    float4 pi = pts[i];
    float d[NS];
#pragma unroll
    for (int s = 0; s < NS; ++s) {
        int j = lane + s * 64;
        float4 pj = pts[j];
        float dist = pi.w + pj.w - 2.f * (pi.x * pj.x + pi.y * pj.y + pi.z * pj.z);
        d[s] = (j == i) ? FINF : dist;
    }
    int* orow = knn + ((size_t)(b * V_out + i)) * K;
    for (int r = 0; r < K; ++r) {
        // per-lane local argmin over slots (static indices)
        float bd = d[0]; int bs = 0;
#pragma unroll
        for (int s = 1; s < NS; ++s) { if (d[s] < bd) { bd = d[s]; bs = s; } }
        float rd = bd; int ri = bs * 64 + lane;
        // wave argmin butterfly; all lanes converge to same (rd, ri)
#pragma unroll
        for (int off = 32; off > 0; off >>= 1) {
            float od = __shfl_xor(rd, off, 64);
            int oi = __shfl_xor(ri, off, 64);
            if (od < rd || (od == rd && oi < ri)) { rd = od; ri = oi; }
        }
        if (lane == 0) orow[r] = ri;
        // winning lane invalidates its slot (static-index predicated stores)
        if (lane == (ri & 63)) {
            int ks = ri >> 6;
#pragma unroll
            for (int s = 0; s < NS; ++s) { if (s == ks) d[s] = FINF; }
        }
    }
}

// ---------------- normalized neighbor directions ----------------
__global__ __launch_bounds__(TPB) void ndir_kernel(const int* __restrict__ knn, const float* __restrict__ verts,
                            float* __restrict__ ndir, int B, int Vst, int K) {
    int t = blockIdx.x * blockDim.x + threadIdx.x;
    if (t >= B * Vst * K) return;
    int row = t / K;
    int b = row / Vst, i = row % Vst;
    int j = knn[t];
    const float* vb = verts + (size_t)b * 1024 * 3;
    float dx = vb[j * 3]     - vb[i * 3];
    float dy = vb[j * 3 + 1] - vb[i * 3 + 1];
    float dz = vb[j * 3 + 2] - vb[i * 3 + 2];
    float nrm = sqrtf(dx * dx + dy * dy + dz * dz);
    float inv = 1.f / fmaxf(nrm, 1e-12f);
    ndir[(size_t)t * 3] = dx * inv;
    ndir[(size_t)t * 3 + 1] = dy * inv;
    ndir[(size_t)t * 3 + 2] = dz * inv;
}

// ---------------- conv_surface: fm0 = max_n relu(ndir . sdir_c) ----------------
__global__ __launch_bounds__(TPB) void conv_surface_kernel(const float* __restrict__ ndir, const float* __restrict__ dir,
                                    float* __restrict__ fm0, int rows, int K, int C) {
    int t = blockIdx.x * blockDim.x + threadIdx.x;
    if (t >= rows * C) return;
    int row = t / C, c = t % C;
    float d0 = dir[c], d1 = dir[C + c], d2 = dir[2 * C + c];
    float inv = 1.f / fmaxf(sqrtf(d0 * d0 + d1 * d1 + d2 * d2), 1e-12f);
    d0 *= inv; d1 *= inv; d2 *= inv;
    float m = -FINF;
    const float* nd = ndir + (size_t)row * K * 3;
    for (int n = 0; n < K; ++n) {
        float th = fmaxf(nd[n * 3] * d0 + nd[n * 3 + 1] * d1 + nd[n * 3 + 2] * d2, 0.f);
        m = fmaxf(m, th);
    }
    fm0[t] = m; // relu(max of relus) == max
}

// ---------------- GEMM, 4 rows x 4 cols per thread: out = in @ w + bias ----------------
// in: rows x Cin, w: Cin x Cw (row-major), rows % 4 == 0, Cw % 4 == 0
__global__ __launch_bounds__(TPB) void gemm_bias4_kernel(const float* __restrict__ in, const float* __restrict__ w,
                                 const float* __restrict__ bias, float* __restrict__ out,
                                 int rows, int Cin, int Cw) {
    int t = blockIdx.x * blockDim.x + threadIdx.x;
    int nc4 = Cw >> 2, nr4 = rows >> 2;
    if (t >= nr4 * nc4) return;
    int rg = t / nc4, c4 = (t % nc4) * 4;
    int r0 = rg * 4;
    float4 bv = *(const float4*)(bias + c4);
    float4 a0 = bv, a1 = bv, a2 = bv, a3 = bv;
    const float* i0 = in + (size_t)r0 * Cin;
    for (int k = 0; k < Cin; ++k) {
        float4 wv = *(const float4*)(w + (size_t)k * Cw + c4);
        float x0 = i0[k], x1 = i0[Cin + k], x2 = i0[2 * Cin + k], x3 = i0[3 * Cin + k];
        a0.x += x0 * wv.x; a0.y += x0 * wv.y; a0.z += x0 * wv.z; a0.w += x0 * wv.w;
        a1.x += x1 * wv.x; a1.y += x1 * wv.y; a1.z += x1 * wv.z; a1.w += x1 * wv.w;
        a2.x += x2 * wv.x; a2.y += x2 * wv.y; a2.z += x2 * wv.z; a2.w += x2 * wv.w;
        a3.x += x3 * wv.x; a3.y += x3 * wv.y; a3.z += x3 * wv.z; a3.w += x3 * wv.w;
    }
    *(float4*)(out + (size_t)r0 * Cw + c4) = a0;
    *(float4*)(out + (size_t)(r0 + 1) * Cw + c4) = a1;
    *(float4*)(out + (size_t)(r0 + 2) * Cw + c4) = a2;
    *(float4*)(out + (size_t)(r0 + 3) * Cw + c4) = a3;
}

// ---------------- conv_layer: center + max_n(theta * support) ----------------
__global__ __launch_bounds__(TPB) void conv_act_kernel(const float* __restrict__ ndir, const int* __restrict__ knn,
                                const float* __restrict__ fout, const float* __restrict__ dir,
                                float* __restrict__ out, int B, int Vst, int K, int Cout) {
    int t = blockIdx.x * blockDim.x + threadIdx.x;
    if (t >= B * Vst * Cout) return;
    int row = t / Cout, c = t % Cout;
    int b = row / Vst;
    float d0 = dir[c], d1 = dir[Cout + c], d2 = dir[2 * Cout + c];
    float inv = 1.f / fmaxf(sqrtf(d0 * d0 + d1 * d1 + d2 * d2), 1e-12f);
    d0 *= inv; d1 *= inv; d2 *= inv;
    int Cw = 2 * Cout;
    float m = -FINF;
    const float* nd = ndir + (size_t)row * K * 3;
    const int* kr = knn + (size_t)row * K;
    for (int n = 0; n < K; ++n) {
        int j = kr[n];
        float th = fmaxf(nd[n * 3] * d0 + nd[n * 3 + 1] * d1 + nd[n * 3 + 2] * d2, 0.f);
        float s = fout[((size_t)(b * Vst + j)) * Cw + Cout + c];
        m = fmaxf(m, th * s);
    }
    out[t] = fout[(size_t)row * Cw + c] + m;
}

// ---------------- BN stats: mean + rsqrt(var+eps) per channel ----------------
__global__ __launch_bounds__(TPB) void bn_stats_kernel(const float* __restrict__ x, float* __restrict__ stats,
                                int rows, int C) {
    int c = blockIdx.x;
    double s = 0.0, ss = 0.0;
    for (int r = threadIdx.x; r < rows; r += blockDim.x) {
        float v = x[(size_t)r * C + c];
        s += v; ss += (double)v * v;
    }
    __shared__ double sh[TPB], sh2[TPB];
    sh[threadIdx.x] = s; sh2[threadIdx.x] = ss;
    __syncthreads();
    for (int off = TPB / 2; off > 0; off >>= 1) {
        if (threadIdx.x < off) { sh[threadIdx.x] += sh[threadIdx.x + off]; sh2[threadIdx.x] += sh2[threadIdx.x + off]; }
        __syncthreads();
    }
    if (threadIdx.x == 0) {
        double m = sh[0] / rows;
        double var = sh2[0] / rows - m * m;
        if (var < 0) var = 0;
        stats[c] = (float)m;
        stats[C + c] = rsqrtf((float)var + 1e-5f);
    }
}

// ---------------- BN apply + relu + fused residual gemm (fm_in @ dwt), 4 rows x 4 cols ----------------
// dwt: Cin x C (transposed dw), rows % 4 == 0, C % 4 == 0
__global__ __launch_bounds__(TPB) void bn_apply_res4_kernel(const float* __restrict__ conv, const float* __restrict__ stats,
                                    const float* __restrict__ fmin, const float* __restrict__ dwt,
                                    float* __restrict__ out, int rows, int C, int Cin) {
    int t = blockIdx.x * blockDim.x + threadIdx.x;
    int nc4 = C >> 2, nr4 = rows >> 2;
    if (t >= nr4 * nc4) return;
    int rg = t / nc4, c4 = (t % nc4) * 4;
    int r0 = rg * 4;
    float4 a0 = make_float4(0.f, 0.f, 0.f, 0.f), a1 = a0, a2 = a0, a3 = a0;
    const float* f0 = fmin + (size_t)r0 * Cin;
    for (int k = 0; k < Cin; ++k) {
        float4 wv = *(const float4*)(dwt + (size_t)k * C + c4);
        float x0 = f0[k], x1 = f0[Cin + k], x2 = f0[2 * Cin + k], x3 = f0[3 * Cin + k];
        a0.x += x0 * wv.x; a0.y += x0 * wv.y; a0.z += x0 * wv.z; a0.w += x0 * wv.w;
        a1.x += x1 * wv.x; a1.y += x1 * wv.y; a1.z += x1 * wv.z; a1.w += x1 * wv.w;
        a2.x += x2 * wv.x; a2.y += x2 * wv.y; a2.z += x2 * wv.z; a2.w += x2 * wv.w;
        a3.x += x3 * wv.x; a3.y += x3 * wv.y; a3.z += x3 * wv.z; a3.w += x3 * wv.w;
    }
    float4 mean = *(const float4*)(stats + c4);
    float4 inv = *(const float4*)(stats + C + c4);
    float4 acc[4] = {a0, a1, a2, a3};
#pragma unroll
    for (int rr = 0; rr < 4; ++rr) {
        float4 cv = *(const float4*)(conv + (size_t)(r0 + rr) * C + c4);
        float4 o;
        o.x = fmaxf((cv.x - mean.x) * inv.x, 0.f) + acc[rr].x;
        o.y = fmaxf((cv.y - mean.y) * inv.y, 0.f) + acc[rr].y;
        o.z = fmaxf((cv.z - mean.z) * inv.z, 0.f) + acc[rr].z;
        o.w = fmaxf((cv.w - mean.w) * inv.w, 0.f) + acc[rr].w;
        *(float4*)(out + (size_t)(r0 + rr) * C + c4) = o;
    }
}

// ---------------- pool: max over 4 NN features, first pn rows ----------------
__global__ __launch_bounds__(TPB) void pool_max_kernel(const float* __restrict__ fm, const int* __restrict__ knn4,
                                float* __restrict__ out, int B, int Vin, int pn, int C) {
    int t = blockIdx.x * blockDim.x + threadIdx.x;
    if (t >= B * pn * C) return;
    int row = t / C, c = t % C;
    int b = row / pn;
    const int* kr = knn4 + (size_t)row * 4;
    float m = -FINF;
    for (int n = 0; n < 4; ++n) {
        int j = kr[n];
        m = fmaxf(m, fm[((size_t)(b * Vin + j)) * C + c]);
    }
    out[t] = m;
}

// ---------------- g = max over vertices ----------------
__global__ __launch_bounds__(TPB) void rowmax_kernel(const float* __restrict__ fm, float* __restrict__ g,
                              int B, int V, int C) {
    int t = blockIdx.x * blockDim.x + threadIdx.x;
    if (t >= B * C) return;
    int b = t / C, c = t % C;
    float m = -FINF;
    for (int i = 0; i < V; ++i) m = fmaxf(m, fm[((size_t)(b * V + i)) * C + c]);
    g[t] = m;
}

// ---------------- out[r,c] = in[r,:]@w[c,:] + bias[c]  (w row-major Cout x Cin) ----------------
__global__ __launch_bounds__(TPB) void gemm_t_bias_kernel(const float* __restrict__ in, const float* __restrict__ w,
                                   const float* __restrict__ bias, float* __restrict__ out,
                                   int rows, int Cin, int Cout) {
    int t = blockIdx.x * blockDim.x + threadIdx.x;
    if (t >= rows * Cout) return;
    int r = t / Cout, c = t % Cout;
    const float4* a = (const float4*)(in + (size_t)r * Cin);
    const float4* wr = (const float4*)(w + (size_t)c * Cin);
    float acc = 0.f;
    int n4 = Cin >> 2;
    for (int k = 0; k < n4; ++k) {
        float4 av = a[k], wv = wr[k];
        acc += av.x * wv.x + av.y * wv.y + av.z * wv.z + av.w * wv.w;
    }
    out[t] = acc + bias[c];
}

// ---------------- classifier BN stats over batch (32) ----------------
__global__ __launch_bounds__(TPB) void cls_bn_stats_kernel(const float* __restrict__ h, float* __restrict__ stats) {
    int c = blockIdx.x * blockDim.x + threadIdx.x;
    if (c >= 256) return;
    float s = 0.f, ss = 0.f;
    for (int b = 0; b < 32; ++b) {
        float v = h[(size_t)b * 256 + c];
        s += v; ss += v * v;
    }
    float m = s / 32.f;
    float var = ss / 32.f - m * m;
    if (var < 0.f) var = 0.f;
    stats[c] = m;
    stats[256 + c] = rsqrtf(var + 1e-5f);
}

// ---------------- final: relu(bn(h)*g+beta) @ w2^T + b2 ----------------
__global__ __launch_bounds__(TPB) void cls_final_kernel(const float* __restrict__ h, const float* __restrict__ stats,
                                 const float* __restrict__ gam, const float* __restrict__ beta,
                                 const float* __restrict__ w2, const float* __restrict__ b2,
                                 float* __restrict__ out) {
    int t = blockIdx.x * blockDim.x + threadIdx.x;
    if (t >= 32 * 40) return;
    int b = t / 40, o = t % 40;
    float acc = b2[o];
    for (int c = 0; c < 256; ++c) {
        float v = fmaxf((h[(size_t)b * 256 + c] - stats[c]) * stats[256 + c] * gam[c] + beta[c], 0.f);
        acc += v * w2[(size_t)o * 256 + c];
    }
    out[t] = acc;
}

extern "C" void kernel_launch(void* const* d_in, const int* in_sizes, int n_in,
                              void* d_out, int out_size, void* d_ws, size_t ws_size,
                              hipStream_t stream) {
    const float* vertices = (const float*)d_in[0];
    const float* c0_dir = (const float*)d_in[1];
    const float* c1_w  = (const float*)d_in[2];
    const float* c1_b  = (const float*)d_in[3];
    const float* c1_dir = (const float*)d_in[4];
    const float* d1_w  = (const float*)d_in[5];
    const float* c2_w  = (const float*)d_in[6];
    const float* c2_b  = (const float*)d_in[7];
    const float* c2_dir = (const float*)d_in[8];
    const float* d2_w  = (const float*)d_in[9];
    const float* c3_w  = (const float*)d_in[10];
    const float* c3_b  = (const float*)d_in[11];
    const float* c3_dir = (const float*)d_in[12];
    const float* d3_w  = (const float*)d_in[13];
    const float* c4_w  = (const float*)d_in[14];
    const float* c4_b  = (const float*)d_in[15];
    const float* c4_dir = (const float*)d_in[16];
    const float* d4_w  = (const float*)d_in[17];
    const float* cls_w1 = (const float*)d_in[18];
    const float* cls_b1 = (const float*)d_in[19];
    const float* cls_g  = (const float*)d_in[20];
    const float* cls_beta = (const float*)d_in[21];
    const float* cls_w2 = (const float*)d_in[22];
    const float* cls_b2 = (const float*)d_in[23];

    const int B = 32;
    float* ws = (float*)d_ws;
    size_t off = 0;
    auto alloc = [&](size_t n) { float* p = ws + off; off += n; return p; };
    float* verts = alloc(98304);            // B*1024*3
    int*   knn   = (int*)alloc(655360);     // max B*1024*20
    float* ndir  = alloc(1966080);          // max B*1024*20*3
    float* fm0   = alloc(1048576);          // B*1024*32
    float* fm1   = alloc(2097152);          // B*1024*64
    float* fm1p  = alloc(524288);           // B*256*64
    float* fm2   = alloc(1048576);          // B*256*128
    float* fm3   = alloc(2097152);          // B*256*256
    float* fm3p  = alloc(524288);           // B*64*256
    float* fm4   = alloc(2097152);          // B*64*1024
    float* fout  = alloc(4194304);          // max B*1024*128 / B*256*512 / B*64*2048
    float* convp = alloc(2097152);          // pre-BN conv out
    float* stats = alloc(2048);             // mean + inv, max C=1024
    float* gbuf  = alloc(32768);            // B*1024
    float* hbuf  = alloc(8192);             // B*256
    float* hstats = alloc(512);
    float* d1t   = alloc(2048);             // 32 x 64   (d1_w^T: Cin x C)
    float* d2t   = alloc(8192);             // 64 x 128
    float* d3t   = alloc(32768);            // 128 x 256
    float* d4t   = alloc(262144);           // 256 x 1024

    // ---- weight transposes (input-only deps) ----
    transpose_mat_kernel<<<nblk(64 * 32), TPB, 0, stream>>>(d1_w, d1t, 64, 32);
    transpose_mat_kernel<<<nblk(128 * 64), TPB, 0, stream>>>(d2_w, d2t, 128, 64);
    transpose_mat_kernel<<<nblk(256 * 128), TPB, 0, stream>>>(d3_w, d3t, 256, 128);
    transpose_mat_kernel<<<nblk(1024 * 256), TPB, 0, stream>>>(d4_w, d4t, 1024, 256);

    // ---- stage 1 (V=1024) ----
    transpose_verts<<<nblk(B * 1024), TPB, 0, stream>>>(vertices, verts, B, 1024);
    knn_wave_kernel<20, 16><<<dim3(256, B), TPB, 0, stream>>>(verts, knn, 1024);
    ndir_kernel<<<nblk((long)B * 1024 * 20), TPB, 0, stream>>>(knn, verts, ndir, B, 1024, 20);
    conv_surface_kernel<<<nblk((long)B * 1024 * 32), TPB, 0, stream>>>(ndir, c0_dir, fm0, B * 1024, 20, 32);
    gemm_bias4_kernel<<<nblk((long)(B * 1024 / 4) * 32), TPB, 0, stream>>>(fm0, c1_w, c1_b, fout, B * 1024, 32, 128);
    conv_act_kernel<<<nblk((long)B * 1024 * 64), TPB, 0, stream>>>(ndir, knn, fout, c1_dir, convp, B, 1024, 20, 64);
    bn_stats_kernel<<<64, TPB, 0, stream>>>(convp, stats, B * 1024, 64);
    bn_apply_res4_kernel<<<nblk((long)(B * 1024 / 4) * 16), TPB, 0, stream>>>(convp, stats, fm0, d1t, fm1, B * 1024, 64, 32);
    // pool 1024 -> 256
    knn_wave_kernel<4, 16><<<dim3(64, B), TPB, 0, stream>>>(verts, knn, 256);
    pool_max_kernel<<<nblk((long)B * 256 * 64), TPB, 0, stream>>>(fm1, knn, fm1p, B, 1024, 256, 64);

    // ---- stage 2 (V=256) ----
    knn_wave_kernel<20, 4><<<dim3(64, B), TPB, 0, stream>>>(verts, knn, 256);
    ndir_kernel<<<nblk((long)B * 256 * 20), TPB, 0, stream>>>(knn, verts, ndir, B, 256, 20);
    gemm_bias4_kernel<<<nblk((long)(B * 256 / 4) * 64), TPB, 0, stream>>>(fm1p, c2_w, c2_b, fout, B * 256, 64, 256);
    conv_act_kernel<<<nblk((long)B * 256 * 128), TPB, 0, stream>>>(ndir, knn, fout, c2_dir, convp, B, 256, 20, 128);
    bn_stats_kernel<<<128, TPB, 0, stream>>>(convp, stats, B * 256, 128);
    bn_apply_res4_kernel<<<nblk((long)(B * 256 / 4) * 32), TPB, 0, stream>>>(convp, stats, fm1p, d2t, fm2, B * 256, 128, 64);
    gemm_bias4_kernel<<<nblk((long)(B * 256 / 4) * 128), TPB, 0, stream>>>(fm2, c3_w, c3_b, fout, B * 256, 128, 512);
    conv_act_kernel<<<nblk((long)B * 256 * 256), TPB, 0, stream>>>(ndir, knn, fout, c3_dir, convp, B, 256, 20, 256);
    bn_stats_kernel<<<256, TPB, 0, stream>>>(convp, stats, B * 256, 256);
    bn_apply_res4_kernel<<<nblk((long)(B * 256 / 4) * 64), TPB, 0, stream>>>(convp, stats, fm2, d3t, fm3, B * 256, 256, 128);
    // pool 256 -> 64
    knn_wave_kernel<4, 4><<<dim3(16, B), TPB, 0, stream>>>(verts, knn, 64);
    pool_max_kernel<<<nblk((long)B * 64 * 256), TPB, 0, stream>>>(fm3, knn, fm3p, B, 256, 64, 256);

    // ---- stage 3 (V=64) ----
    knn_wave_kernel<20, 1><<<dim3(16, B), TPB, 0, stream>>>(verts, knn, 64);
    ndir_kernel<<<nblk((long)B * 64 * 20), TPB, 0, stream>>>(knn, verts, ndir, B, 64, 20);
    gemm_bias4_kernel<<<nblk((long)(B * 64 / 4) * 512), TPB, 0, stream>>>(fm3p, c4_w, c4_b, fout, B * 64, 256, 2048);
    conv_act_kernel<<<nblk((long)B * 64 * 1024), TPB, 0, stream>>>(ndir, knn, fout, c4_dir, convp, B, 64, 20, 1024);
    bn_stats_kernel<<<1024, TPB, 0, stream>>>(convp, stats, B * 64, 1024);
    bn_apply_res4_kernel<<<nblk((long)(B * 64 / 4) * 256), TPB, 0, stream>>>(convp, stats, fm3p, d4t, fm4, B * 64, 1024, 256);

    // ---- classifier ----
    rowmax_kernel<<<nblk((long)B * 1024), TPB, 0, stream>>>(fm4, gbuf, B, 64, 1024);
    gemm_t_bias_kernel<<<nblk((long)B * 256), TPB, 0, stream>>>(gbuf, cls_w1, cls_b1, hbuf, B, 1024, 256);
    cls_bn_stats_kernel<<<1, TPB, 0, stream>>>(hbuf, hstats);
    cls_final_kernel<<<nblk(32 * 40), TPB, 0, stream>>>(hbuf, hstats, cls_g, cls_beta, cls_w2, cls_b2, (float*)d_out);
}

// Round 6
// 912.363 us; speedup vs baseline: 58.4994x; 1.0013x over previous
//
#include <hip/hip_runtime.h>

#define TPB 256
static inline int nblk(long n) { return (int)((n + TPB - 1) / TPB); }

#define FINF 3.402823466e38f

// ---------------- transpose (B,3,V) -> (B,V,3) ----------------
__global__ __launch_bounds__(TPB) void transpose_verts(const float* __restrict__ vin, float* __restrict__ verts,
                                int B, int V) {
    int t = blockIdx.x * blockDim.x + threadIdx.x;
    if (t >= B * V) return;
    int b = t / V, i = t % V;
    const float* p = vin + (size_t)b * 3 * V;
    float* o = verts + (size_t)t * 3;
    o[0] = p[i]; o[1] = p[V + i]; o[2] = p[2 * V + i];
}

// ---------------- fused weight transposes: d1..d4 (Cout x Cin) -> (Cin x Cout) ----------------
__global__ __launch_bounds__(TPB) void transpose_all_kernel(const float* __restrict__ d1, const float* __restrict__ d2,
                                                            const float* __restrict__ d3, const float* __restrict__ d4,
                                                            float* __restrict__ o1, float* __restrict__ o2,
                                                            float* __restrict__ o3, float* __restrict__ o4) {
    int t = blockIdx.x * blockDim.x + threadIdx.x;
    if (t < 2048) { int r = t / 32, c = t % 32; o1[c * 64 + r] = d1[t]; return; }
    int t2 = t - 2048;
    if (t2 < 8192) { int r = t2 / 64, c = t2 % 64; o2[c * 128 + r] = d2[t2]; return; }
    int t3 = t2 - 8192;
    if (t3 < 32768) { int r = t3 / 128, c = t3 % 128; o3[c * 256 + r] = d3[t3]; return; }
    int t4 = t3 - 32768;
    if (t4 < 262144) { int r = t4 / 256, c = t4 % 256; o4[c * 1024 + r] = d4[t4]; }
}

// ---------------- KNN: wave-per-vertex radix select, K nearest excluding self ----------------
// Positive floats are monotone in their bit patterns: binary-search the K-th
// smallest distance (31 uniform iterations, 1 v_cmp+ballot per slot), then
// ballot-compact the < T set plus lowest-index ties. Neighbor ORDER is
// irrelevant downstream (max over neighbors) - only the set must match.
template <int K, int NS>
__global__ __launch_bounds__(TPB, 1) void knn_radix_kernel(const float* __restrict__ verts,
                                                           int* __restrict__ knn, int V_out) {
    constexpr int VF = NS * 64;
    __shared__ float4 pts[VF]; // (x, y, z, |p|^2)
    int b = blockIdx.y;
    const float* vb = verts + (size_t)b * 1024 * 3;
    for (int j = threadIdx.x; j < VF; j += blockDim.x) {
        float x = vb[j * 3], y = vb[j * 3 + 1], z = vb[j * 3 + 2];
        pts[j] = make_float4(x, y, z, x * x + y * y + z * z);
    }
    __syncthreads();
    int lane = threadIdx.x & 63;
    int i = blockIdx.x * 4 + (threadIdx.x >> 6); // 4 waves/block
    if (i >= V_out) return;
    float4 pi = pts[i];
    unsigned ud[NS];
#pragma unroll
    for (int s = 0; s < NS; ++s) {
        int j = s * 64 + lane;
        float4 pj = pts[j];
        float dist = pi.w + pj.w - 2.f * (pi.x * pj.x + pi.y * pj.y + pi.z * pj.z);
        dist = fmaxf(dist, 0.f); // keep bit-monotone (fp rounding can go < 0)
        ud[s] = (j == i) ? 0xFFFFFFFFu : __float_as_uint(dist);
    }
    // invariant: c(lo) < K <= c(hi), c(m) = #{ud < m}; converges to lo = K-th smallest
    unsigned lo = 0u, hi = 0x7F800000u;
    while (hi - lo > 1u) {
        unsigned mid = lo + ((hi - lo) >> 1);
        int cnt = 0;
#pragma unroll
        for (int s = 0; s < NS; ++s)
            cnt += __popcll(__ballot(ud[s] < mid));
        if (cnt >= K) hi = mid; else lo = mid;
    }
    unsigned T = lo;
    int* orow = knn + ((size_t)(b * V_out + i)) * K;
    unsigned long long lmask = (1ull << lane) - 1ull;
    int base = 0;
#pragma unroll
    for (int s = 0; s < NS; ++s) {
        unsigned long long m = __ballot(ud[s] < T);
        if (ud[s] < T) orow[base + __popcll(m & lmask)] = s * 64 + lane;
        base += __popcll(m);
    }
    int need = K - base; // >= 1 ties at T fill the rest, lowest index first
    int run = 0;
#pragma unroll
    for (int s = 0; s < NS; ++s) {
        unsigned long long m = __ballot(ud[s] == T);
        int r = run + __popcll(m & lmask);
        if (ud[s] == T && r < need) orow[base + r] = s * 64 + lane;
        run += __popcll(m);
    }
}

// ---------------- normalized neighbor directions ----------------
__global__ __launch_bounds__(TPB) void ndir_kernel(const int* __restrict__ knn, const float* __restrict__ verts,
                            float* __restrict__ ndir, int B, int Vst, int K) {
    int t = blockIdx.x * blockDim.x + threadIdx.x;
    if (t >= B * Vst * K) return;
    int row = t / K;
    int b = row / Vst, i = row % Vst;
    int j = knn[t];
    const float* vb = verts + (size_t)b * 1024 * 3;
    float dx = vb[j * 3]     - vb[i * 3];
    float dy = vb[j * 3 + 1] - vb[i * 3 + 1];
    float dz = vb[j * 3 + 2] - vb[i * 3 + 2];
    float nrm = sqrtf(dx * dx + dy * dy + dz * dz);
    float inv = 1.f / fmaxf(nrm, 1e-12f);
    ndir[(size_t)t * 3] = dx * inv;
    ndir[(size_t)t * 3 + 1] = dy * inv;
    ndir[(size_t)t * 3 + 2] = dz * inv;
}

// ---------------- conv_surface: fm0 = max_n relu(ndir . sdir_c) ----------------
__global__ __launch_bounds__(TPB) void conv_surface_kernel(const float* __restrict__ ndir, const float* __restrict__ dir,
                                    float* __restrict__ fm0, int rows, int K, int C) {
    int t = blockIdx.x * blockDim.x + threadIdx.x;
    if (t >= rows * C) return;
    int row = t / C, c = t % C;
    float d0 = dir[c], d1 = dir[C + c], d2 = dir[2 * C + c];
    float inv = 1.f / fmaxf(sqrtf(d0 * d0 + d1 * d1 + d2 * d2), 1e-12f);
    d0 *= inv; d1 *= inv; d2 *= inv;
    float m = -FINF;
    const float* nd = ndir + (size_t)row * K * 3;
    for (int n = 0; n < K; ++n) {
        float th = fmaxf(nd[n * 3] * d0 + nd[n * 3 + 1] * d1 + nd[n * 3 + 2] * d2, 0.f);
        m = fmaxf(m, th);
    }
    fm0[t] = m; // relu(max of relus) == max
}

// ---------------- GEMM, 4 rows x 4 cols per thread: out = in @ w + bias ----------------
__global__ __launch_bounds__(TPB) void gemm_bias4_kernel(const float* __restrict__ in, const float* __restrict__ w,
                                 const float* __restrict__ bias, float* __restrict__ out,
                                 int rows, int Cin, int Cw) {
    int t = blockIdx.x * blockDim.x + threadIdx.x;
    int nc4 = Cw >> 2, nr4 = rows >> 2;
    if (t >= nr4 * nc4) return;
    int rg = t / nc4, c4 = (t % nc4) * 4;
    int r0 = rg * 4;
    float4 bv = *(const float4*)(bias + c4);
    float4 a0 = bv, a1 = bv, a2 = bv, a3 = bv;
    const float* i0 = in + (size_t)r0 * Cin;
    for (int k = 0; k < Cin; ++k) {
        float4 wv = *(const float4*)(w + (size_t)k * Cw + c4);
        float x0 = i0[k], x1 = i0[Cin + k], x2 = i0[2 * Cin + k], x3 = i0[3 * Cin + k];
        a0.x += x0 * wv.x; a0.y += x0 * wv.y; a0.z += x0 * wv.z; a0.w += x0 * wv.w;
        a1.x += x1 * wv.x; a1.y += x1 * wv.y; a1.z += x1 * wv.z; a1.w += x1 * wv.w;
        a2.x += x2 * wv.x; a2.y += x2 * wv.y; a2.z += x2 * wv.z; a2.w += x2 * wv.w;
        a3.x += x3 * wv.x; a3.y += x3 * wv.y; a3.z += x3 * wv.z; a3.w += x3 * wv.w;
    }
    *(float4*)(out + (size_t)r0 * Cw + c4) = a0;
    *(float4*)(out + (size_t)(r0 + 1) * Cw + c4) = a1;
    *(float4*)(out + (size_t)(r0 + 2) * Cw + c4) = a2;
    *(float4*)(out + (size_t)(r0 + 3) * Cw + c4) = a3;
}

// ---------------- conv_layer: center + max_n(theta * support) ----------------
__global__ __launch_bounds__(TPB) void conv_act_kernel(const float* __restrict__ ndir, const int* __restrict__ knn,
                                const float* __restrict__ fout, const float* __restrict__ dir,
                                float* __restrict__ out, int B, int Vst, int K, int Cout) {
    int t = blockIdx.x * blockDim.x + threadIdx.x;
    if (t >= B * Vst * Cout) return;
    int row = t / Cout, c = t % Cout;
    int b = row / Vst;
    float d0 = dir[c], d1 = dir[Cout + c], d2 = dir[2 * Cout + c];
    float inv = 1.f / fmaxf(sqrtf(d0 * d0 + d1 * d1 + d2 * d2), 1e-12f);
    d0 *= inv; d1 *= inv; d2 *= inv;
    int Cw = 2 * Cout;
    float m = -FINF;
    const float* nd = ndir + (size_t)row * K * 3;
    const int* kr = knn + (size_t)row * K;
    for (int n = 0; n < K; ++n) {
        int j = kr[n];
        float th = fmaxf(nd[n * 3] * d0 + nd[n * 3 + 1] * d1 + nd[n * 3 + 2] * d2, 0.f);
        float s = fout[((size_t)(b * Vst + j)) * Cw + Cout + c];
        m = fmaxf(m, th * s);
    }
    out[t] = fout[(size_t)row * Cw + c] + m;
}

// ---------------- BN stats, two-pass: coalesced float partials + double combine ----------------
__global__ __launch_bounds__(TPB) void bn_partial_kernel(const float* __restrict__ x, float* __restrict__ partial,
                                                         int rows, int C, int nsplit) {
    int t = blockIdx.x * blockDim.x + threadIdx.x;
    if (t >= C * nsplit) return;
    int c = t % C, sp = t / C;
    int chunk = rows / nsplit;
    int r0 = sp * chunk;
    float s = 0.f, ss = 0.f;
    for (int r = r0; r < r0 + chunk; ++r) {
        float v = x[(size_t)r * C + c];
        s += v; ss += v * v;
    }
    partial[(size_t)sp * 2 * C + c] = s;
    partial[(size_t)sp * 2 * C + C + c] = ss;
}

__global__ __launch_bounds__(TPB) void bn_finalize_kernel(const float* __restrict__ partial, float* __restrict__ stats,
                                                          int rows, int C, int nsplit) {
    int c = blockIdx.x * blockDim.x + threadIdx.x;
    if (c >= C) return;
    double s = 0.0, ss = 0.0;
    for (int sp = 0; sp < nsplit; ++sp) {
        s += partial[(size_t)sp * 2 * C + c];
        ss += partial[(size_t)sp * 2 * C + C + c];
    }
    double m = s / rows;
    double var = ss / rows - m * m;
    if (var < 0) var = 0;
    stats[c] = (float)m;
    stats[C + c] = rsqrtf((float)var + 1e-5f);
}

// ---------------- BN apply + relu + fused residual gemm (fm_in @ dwt), 4 rows x 4 cols ----------------
__global__ __launch_bounds__(TPB) void bn_apply_res4_kernel(const float* __restrict__ conv, const float* __restrict__ stats,
                                    const float* __restrict__ fmin, const float* __restrict__ dwt,
                                    float* __restrict__ out, int rows, int C, int Cin) {
    int t = blockIdx.x * blockDim.x + threadIdx.x;
    int nc4 = C >> 2, nr4 = rows >> 2;
    if (t >= nr4 * nc4) return;
    int rg = t / nc4, c4 = (t % nc4) * 4;
    int r0 = rg * 4;
    float4 a0 = make_float4(0.f, 0.f, 0.f, 0.f), a1 = a0, a2 = a0, a3 = a0;
    const float* f0 = fmin + (size_t)r0 * Cin;
    for (int k = 0; k < Cin; ++k) {
        float4 wv = *(const float4*)(dwt + (size_t)k * C + c4);
        float x0 = f0[k], x1 = f0[Cin + k], x2 = f0[2 * Cin + k], x3 = f0[3 * Cin + k];
        a0.x += x0 * wv.x; a0.y += x0 * wv.y; a0.z += x0 * wv.z; a0.w += x0 * wv.w;
        a1.x += x1 * wv.x; a1.y += x1 * wv.y; a1.z += x1 * wv.z; a1.w += x1 * wv.w;
        a2.x += x2 * wv.x; a2.y += x2 * wv.y; a2.z += x2 * wv.z; a2.w += x2 * wv.w;
        a3.x += x3 * wv.x; a3.y += x3 * wv.y; a3.z += x3 * wv.z; a3.w += x3 * wv.w;
    }
    float4 mean = *(const float4*)(stats + c4);
    float4 inv = *(const float4*)(stats + C + c4);
    float4 acc[4] = {a0, a1, a2, a3};
#pragma unroll
    for (int rr = 0; rr < 4; ++rr) {
        float4 cv = *(const float4*)(conv + (size_t)(r0 + rr) * C + c4);
        float4 o;
        o.x = fmaxf((cv.x - mean.x) * inv.x, 0.f) + acc[rr].x;
        o.y = fmaxf((cv.y - mean.y) * inv.y, 0.f) + acc[rr].y;
        o.z = fmaxf((cv.z - mean.z) * inv.z, 0.f) + acc[rr].z;
        o.w = fmaxf((cv.w - mean.w) * inv.w, 0.f) + acc[rr].w;
        *(float4*)(out + (size_t)(r0 + rr) * C + c4) = o;
    }
}

// ---------------- pool: max over 4 NN features, first pn rows ----------------
__global__ __launch_bounds__(TPB) void pool_max_kernel(const float* __restrict__ fm, const int* __restrict__ knn4,
                                float* __restrict__ out, int B, int Vin, int pn, int C) {
    int t = blockIdx.x * blockDim.x + threadIdx.x;
    if (t >= B * pn * C) return;
    int row = t / C, c = t % C;
    int b = row / pn;
    const int* kr = knn4 + (size_t)row * 4;
    float m = -FINF;
    for (int n = 0; n < 4; ++n) {
        int j = kr[n];
        m = fmaxf(m, fm[((size_t)(b * Vin + j)) * C + c]);
    }
    out[t] = m;
}

// ---------------- g = max over vertices ----------------
__global__ __launch_bounds__(TPB) void rowmax_kernel(const float* __restrict__ fm, float* __restrict__ g,
                              int B, int V, int C) {
    int t = blockIdx.x * blockDim.x + threadIdx.x;
    if (t >= B * C) return;
    int b = t / C, c = t % C;
    float m = -FINF;
    for (int i = 0; i < V; ++i) m = fmaxf(m, fm[((size_t)(b * V + i)) * C + c]);
    g[t] = m;
}

// ---------------- wave-per-output: out[r,c] = in[r,:]@w[c,:] + bias[c] ----------------
__global__ __launch_bounds__(TPB, 1) void gemm_t_wave_kernel(const float* __restrict__ in, const float* __restrict__ w,
                                   const float* __restrict__ bias, float* __restrict__ out,
                                   int rows, int Cin, int Cout) {
    int wid = (blockIdx.x * blockDim.x + threadIdx.x) >> 6;
    int lane = threadIdx.x & 63;
    if (wid >= rows * Cout) return;
    int r = wid / Cout, c = wid % Cout;
    const float4* a = (const float4*)(in + (size_t)r * Cin);
    const float4* wr = (const float4*)(w + (size_t)c * Cin);
    int n4 = Cin >> 2;
    float acc = 0.f;
    for (int k = lane; k < n4; k += 64) {
        float4 av = a[k], wv = wr[k];
        acc += av.x * wv.x + av.y * wv.y + av.z * wv.z + av.w * wv.w;
    }
#pragma unroll
    for (int off = 32; off > 0; off >>= 1) acc += __shfl_xor(acc, off, 64);
    if (lane == 0) out[wid] = acc + bias[c];
}

// ---------------- classifier BN stats over batch (32) ----------------
__global__ __launch_bounds__(TPB) void cls_bn_stats_kernel(const float* __restrict__ h, float* __restrict__ stats) {
    int c = blockIdx.x * blockDim.x + threadIdx.x;
    if (c >= 256) return;
    float s = 0.f, ss = 0.f;
    for (int b = 0; b < 32; ++b) {
        float v = h[(size_t)b * 256 + c];
        s += v; ss += v * v;
    }
    float m = s / 32.f;
    float var = ss / 32.f - m * m;
    if (var < 0.f) var = 0.f;
    stats[c] = m;
    stats[256 + c] = rsqrtf(var + 1e-5f);
}

// ---------------- final: wave-per-output relu(bn(h)*g+beta) @ w2^T + b2 ----------------
__global__ __launch_bounds__(TPB, 1) void cls_final_wave_kernel(const float* __restrict__ h, const float* __restrict__ stats,
                                 const float* __restrict__ gam, const float* __restrict__ beta,
                                 const float* __restrict__ w2, const float* __restrict__ b2,
                                 float* __restrict__ out) {
    int wid = (blockIdx.x * blockDim.x + threadIdx.x) >> 6;
    int lane = threadIdx.x & 63;
    if (wid >= 32 * 40) return;
    int b = wid / 40, o = wid % 40;
    float acc = 0.f;
#pragma unroll
    for (int kk = 0; kk < 4; ++kk) {
        int c = lane + kk * 64;
        float v = fmaxf((h[b * 256 + c] - stats[c]) * stats[256 + c] * gam[c] + beta[c], 0.f);
        acc += v * w2[o * 256 + c];
    }
#pragma unroll
    for (int off = 32; off > 0; off >>= 1) acc += __shfl_xor(acc, off, 64);
    if (lane == 0) out[wid] = acc + b2[o];
}

extern "C" void kernel_launch(void* const* d_in, const int* in_sizes, int n_in,
                              void* d_out, int out_size, void* d_ws, size_t ws_size,
                              hipStream_t stream) {
    const float* vertices = (const float*)d_in[0];
    const float* c0_dir = (const float*)d_in[1];
    const float* c1_w  = (const float*)d_in[2];
    const float* c1_b  = (const float*)d_in[3];
    const float* c1_dir = (const float*)d_in[4];
    const float* d1_w  = (const float*)d_in[5];
    const float* c2_w  = (const float*)d_in[6];
    const float* c2_b  = (const float*)d_in[7];
    const float* c2_dir = (const float*)d_in[8];
    const float* d2_w  = (const float*)d_in[9];
    const float* c3_w  = (const float*)d_in[10];
    const float* c3_b  = (const float*)d_in[11];
    const float* c3_dir = (const float*)d_in[12];
    const float* d3_w  = (const float*)d_in[13];
    const float* c4_w  = (const float*)d_in[14];
    const float* c4_b  = (const float*)d_in[15];
    const float* c4_dir = (const float*)d_in[16];
    const float* d4_w  = (const float*)d_in[17];
    const float* cls_w1 = (const float*)d_in[18];
    const float* cls_b1 = (const float*)d_in[19];
    const float* cls_g  = (const float*)d_in[20];
    const float* cls_beta = (const float*)d_in[21];
    const float* cls_w2 = (const float*)d_in[22];
    const float* cls_b2 = (const float*)d_in[23];

    const int B = 32;
    float* ws = (float*)d_ws;
    size_t off = 0;
    auto alloc = [&](size_t n) { float* p = ws + off; off += n; return p; };
    float* verts = alloc(98304);            // B*1024*3
    int*   knn   = (int*)alloc(655360);     // max B*1024*20
    float* ndir  = alloc(1966080);          // max B*1024*20*3
    float* fm0   = alloc(1048576);          // B*1024*32
    float* fm1   = alloc(2097152);          // B*1024*64
    float* fm1p  = alloc(524288);           // B*256*64
    float* fm2   = alloc(1048576);          // B*256*128
    float* fm3   = alloc(2097152);          // B*256*256
    float* fm3p  = alloc(524288);           // B*64*256
    float* fm4   = alloc(2097152);          // B*64*1024
    float* fout  = alloc(4194304);          // max B*1024*128 / B*256*512 / B*64*2048
    float* convp = alloc(2097152);          // pre-BN conv out
    float* stats = alloc(2048);             // mean + inv, max C=1024
    float* gbuf  = alloc(32768);            // B*1024
    float* hbuf  = alloc(8192);             // B*256
    float* hstats = alloc(512);
    float* d1t   = alloc(2048);             // 32 x 64   (d1_w^T: Cin x C)
    float* d2t   = alloc(8192);             // 64 x 128
    float* d3t   = alloc(32768);            // 128 x 256
    float* d4t   = alloc(262144);           // 256 x 1024
    float* partial = alloc(65536);          // bn partials, max 2*C*nsplit

    // ---- weight transposes (input-only deps), fused ----
    transpose_all_kernel<<<nblk(2048 + 8192 + 32768 + 262144), TPB, 0, stream>>>(
        d1_w, d2_w, d3_w, d4_w, d1t, d2t, d3t, d4t);

    // ---- stage 1 (V=1024) ----
    transpose_verts<<<nblk(B * 1024), TPB, 0, stream>>>(vertices, verts, B, 1024);
    knn_radix_kernel<20, 16><<<dim3(256, B), TPB, 0, stream>>>(verts, knn, 1024);
    ndir_kernel<<<nblk((long)B * 1024 * 20), TPB, 0, stream>>>(knn, verts, ndir, B, 1024, 20);
    conv_surface_kernel<<<nblk((long)B * 1024 * 32), TPB, 0, stream>>>(ndir, c0_dir, fm0, B * 1024, 20, 32);
    gemm_bias4_kernel<<<nblk((long)(B * 1024 / 4) * 32), TPB, 0, stream>>>(fm0, c1_w, c1_b, fout, B * 1024, 32, 128);
    conv_act_kernel<<<nblk((long)B * 1024 * 64), TPB, 0, stream>>>(ndir, knn, fout, c1_dir, convp, B, 1024, 20, 64);
    bn_partial_kernel<<<nblk(64 * 256), TPB, 0, stream>>>(convp, partial, B * 1024, 64, 256);
    bn_finalize_kernel<<<nblk(64), TPB, 0, stream>>>(partial, stats, B * 1024, 64, 256);
    bn_apply_res4_kernel<<<nblk((long)(B * 1024 / 4) * 16), TPB, 0, stream>>>(convp, stats, fm0, d1t, fm1, B * 1024, 64, 32);
    // pool 1024 -> 256
    knn_radix_kernel<4, 16><<<dim3(64, B), TPB, 0, stream>>>(verts, knn, 256);
    pool_max_kernel<<<nblk((long)B * 256 * 64), TPB, 0, stream>>>(fm1, knn, fm1p, B, 1024, 256, 64);

    // ---- stage 2 (V=256) ----
    knn_radix_kernel<20, 4><<<dim3(64, B), TPB, 0, stream>>>(verts, knn, 256);
    ndir_kernel<<<nblk((long)B * 256 * 20), TPB, 0, stream>>>(knn, verts, ndir, B, 256, 20);
    gemm_bias4_kernel<<<nblk((long)(B * 256 / 4) * 64), TPB, 0, stream>>>(fm1p, c2_w, c2_b, fout, B * 256, 64, 256);
    conv_act_kernel<<<nblk((long)B * 256 * 128), TPB, 0, stream>>>(ndir, knn, fout, c2_dir, convp, B, 256, 20, 128);
    bn_partial_kernel<<<nblk(128 * 128), TPB, 0, stream>>>(convp, partial, B * 256, 128, 128);
    bn_finalize_kernel<<<nblk(128), TPB, 0, stream>>>(partial, stats, B * 256, 128, 128);
    bn_apply_res4_kernel<<<nblk((long)(B * 256 / 4) * 32), TPB, 0, stream>>>(convp, stats, fm1p, d2t, fm2, B * 256, 128, 64);
    gemm_bias4_kernel<<<nblk((long)(B * 256 / 4) * 128), TPB, 0, stream>>>(fm2, c3_w, c3_b, fout, B * 256, 128, 512);
    conv_act_kernel<<<nblk((long)B * 256 * 256), TPB, 0, stream>>>(ndir, knn, fout, c3_dir, convp, B, 256, 20, 256);
    bn_partial_kernel<<<nblk(256 * 128), TPB, 0, stream>>>(convp, partial, B * 256, 256, 128);
    bn_finalize_kernel<<<nblk(256), TPB, 0, stream>>>(partial, stats, B * 256, 256, 128);
    bn_apply_res4_kernel<<<nblk((long)(B * 256 / 4) * 64), TPB, 0, stream>>>(convp, stats, fm2, d3t, fm3, B * 256, 256, 128);
    // pool 256 -> 64
    knn_radix_kernel<4, 4><<<dim3(16, B), TPB, 0, stream>>>(verts, knn, 64);
    pool_max_kernel<<<nblk((long)B * 64 * 256), TPB, 0, stream>>>(fm3, knn, fm3p, B, 256, 64, 256);

    // ---- stage 3 (V=64) ----
    knn_radix_kernel<20, 1><<<dim3(16, B), TPB, 0, stream>>>(verts, knn, 64);
    ndir_kernel<<<nblk((long)B * 64 * 20), TPB, 0, stream>>>(knn, verts, ndir, B, 64, 20);
    gemm_bias4_kernel<<<nblk((long)(B * 64 / 4) * 512), TPB, 0, stream>>>(fm3p, c4_w, c4_b, fout, B * 64, 256, 2048);
    conv_act_kernel<<<nblk((long)B * 64 * 1024), TPB, 0, stream>>>(ndir, knn, fout, c4_dir, convp, B, 64, 20, 1024);
    bn_partial_kernel<<<nblk(1024 * 32), TPB, 0, stream>>>(convp, partial, B * 64, 1024, 32);
    bn_finalize_kernel<<<nblk(1024), TPB, 0, stream>>>(partial, stats, B * 64, 1024, 32);
    bn_apply_res4_kernel<<<nblk((long)(B * 64 / 4) * 256), TPB, 0, stream>>>(convp, stats, fm3p, d4t, fm4, B * 64, 1024, 256);

    // ---- classifier ----
    rowmax_kernel<<<nblk((long)B * 1024), TPB, 0, stream>>>(fm4, gbuf, B, 64, 1024);
    gemm_t_wave_kernel<<<nblk((long)32 * 256 * 64), TPB, 0, stream>>>(gbuf, cls_w1, cls_b1, hbuf, 32, 1024, 256);
    cls_bn_stats_kernel<<<1, TPB, 0, stream>>>(hbuf, hstats);
    cls_final_wave_kernel<<<nblk((long)32 * 40 * 64), TPB, 0, stream>>>(hbuf, hstats, cls_g, cls_beta, cls_w2, cls_b2, (float*)d_out);
}

// Round 7
// 710.827 us; speedup vs baseline: 75.0854x; 1.2835x over previous
//
#include <hip/hip_runtime.h>

#define TPB 256
static inline int nblk(long n) { return (int)((n + TPB - 1) / TPB); }

#define FINF 3.402823466e38f

// ---------------- transpose (B,3,V) -> (B,V,3) ----------------
__global__ __launch_bounds__(TPB) void transpose_verts(const float* __restrict__ vin, float* __restrict__ verts,
                                int B, int V) {
    int t = blockIdx.x * blockDim.x + threadIdx.x;
    if (t >= B * V) return;
    int b = t / V, i = t % V;
    const float* p = vin + (size_t)b * 3 * V;
    float* o = verts + (size_t)t * 3;
    o[0] = p[i]; o[1] = p[V + i]; o[2] = p[2 * V + i];
}

// ---------------- fused weight transposes: d1..d4 (Cout x Cin) -> (Cin x Cout) ----------------
__global__ __launch_bounds__(TPB) void transpose_all_kernel(const float* __restrict__ d1, const float* __restrict__ d2,
                                                            const float* __restrict__ d3, const float* __restrict__ d4,
                                                            float* __restrict__ o1, float* __restrict__ o2,
                                                            float* __restrict__ o3, float* __restrict__ o4) {
    int t = blockIdx.x * blockDim.x + threadIdx.x;
    if (t < 2048) { int r = t / 32, c = t % 32; o1[c * 64 + r] = d1[t]; return; }
    int t2 = t - 2048;
    if (t2 < 8192) { int r = t2 / 64, c = t2 % 64; o2[c * 128 + r] = d2[t2]; return; }
    int t3 = t2 - 8192;
    if (t3 < 32768) { int r = t3 / 128, c = t3 % 128; o3[c * 256 + r] = d3[t3]; return; }
    int t4 = t3 - 32768;
    if (t4 < 262144) { int r = t4 / 256, c = t4 % 256; o4[c * 1024 + r] = d4[t4]; }
}

// ---------------- KNN radix-select + fused neighbor directions ----------------
// Wave-per-vertex. Binary search on float bit patterns for the K-th smallest
// distance (count via ballots), then ballot-compaction. Lanes 0..K-1 then
// compute normalized directions straight from the LDS point cache (WDIR).
// Grids are exact: V_out is always a multiple of 4 blocks' wave count.
template <int K, int NS, bool WDIR>
__global__ __launch_bounds__(TPB, 1) void knn_radix_kernel(const float* __restrict__ verts,
                                                           int* __restrict__ knn, float* __restrict__ ndir,
                                                           int V_out) {
    constexpr int VF = NS * 64;
    __shared__ float4 pts[VF]; // (x, y, z, |p|^2)
    __shared__ int sidx[4][K];
    int b = blockIdx.y;
    const float* vb = verts + (size_t)b * 1024 * 3;
    for (int j = threadIdx.x; j < VF; j += blockDim.x) {
        float x = vb[j * 3], y = vb[j * 3 + 1], z = vb[j * 3 + 2];
        pts[j] = make_float4(x, y, z, x * x + y * y + z * z);
    }
    __syncthreads();
    int lane = threadIdx.x & 63;
    int w = threadIdx.x >> 6;
    int i = blockIdx.x * 4 + w; // 4 waves/block, grid sized exactly
    if (i >= V_out) return;
    float4 pi = pts[i];
    unsigned ud[NS];
    unsigned umax = 0u, umin = 0xFFFFFFFFu;
#pragma unroll
    for (int s = 0; s < NS; ++s) {
        int j = s * 64 + lane;
        float4 pj = pts[j];
        float dist = pi.w + pj.w - 2.f * (pi.x * pj.x + pi.y * pj.y + pi.z * pj.z);
        dist = fmaxf(dist, 0.f); // keep bit-monotone (fp rounding can go < 0)
        unsigned v = (j == i) ? 0xFFFFFFFFu : __float_as_uint(dist);
        ud[s] = v;
        if (v != 0xFFFFFFFFu) { umax = v > umax ? v : umax; umin = v < umin ? v : umin; }
    }
    // wave min/max of real distances -> tight initial bounds
#pragma unroll
    for (int off = 32; off > 0; off >>= 1) {
        unsigned om = (unsigned)__shfl_xor((int)umax, off, 64);
        unsigned on = (unsigned)__shfl_xor((int)umin, off, 64);
        umax = om > umax ? om : umax;
        umin = on < umin ? on : umin;
    }
    // invariant: count(lo) < K <= count(hi); count(m) = #{ud < m}
    unsigned lo = umin, hi = umax + 1u;
    while (hi - lo > 1u) {
        unsigned mid = lo + ((hi - lo) >> 1);
        int cnt = 0;
#pragma unroll
        for (int s = 0; s < NS; ++s)
            cnt += __popcll(__ballot(ud[s] < mid));
        if (cnt >= K) hi = mid; else lo = mid;
    }
    unsigned T = lo;
    int* orow = knn + ((size_t)(b * V_out + i)) * K;
    unsigned long long lmask = (1ull << lane) - 1ull;
    int base = 0;
#pragma unroll
    for (int s = 0; s < NS; ++s) {
        unsigned long long m = __ballot(ud[s] < T);
        if (ud[s] < T) {
            int p = base + __popcll(m & lmask);
            orow[p] = s * 64 + lane;
            sidx[w][p] = s * 64 + lane;
        }
        base += __popcll(m);
    }
    int need = K - base; // >= 1 ties at T fill the rest, lowest index first
    int run = 0;
#pragma unroll
    for (int s = 0; s < NS; ++s) {
        unsigned long long m = __ballot(ud[s] == T);
        int r = run + __popcll(m & lmask);
        if (ud[s] == T && r < need) {
            orow[base + r] = s * 64 + lane;
            sidx[w][base + r] = s * 64 + lane;
        }
        run += __popcll(m);
    }
    if (WDIR) {
        // wave-synchronous LDS read-after-write (same wave wrote sidx[w])
        if (lane < K) {
            int j = sidx[w][lane];
            float4 pj = pts[j];
            float dx = pj.x - pi.x, dy = pj.y - pi.y, dz = pj.z - pi.z;
            float inv = 1.f / fmaxf(sqrtf(dx * dx + dy * dy + dz * dz), 1e-12f);
            float* o = ndir + ((size_t)(b * V_out + i) * K + lane) * 3;
            o[0] = dx * inv; o[1] = dy * inv; o[2] = dz * inv;
        }
    }
}

// ---------------- conv_surface: fm0 = max_n relu(ndir . sdir_c) ----------------
__global__ __launch_bounds__(TPB) void conv_surface_kernel(const float* __restrict__ ndir, const float* __restrict__ dir,
                                    float* __restrict__ fm0, int rows, int K, int C) {
    int t = blockIdx.x * blockDim.x + threadIdx.x;
    if (t >= rows * C) return;
    int row = t / C, c = t % C;
    float d0 = dir[c], d1 = dir[C + c], d2 = dir[2 * C + c];
    float inv = 1.f / fmaxf(sqrtf(d0 * d0 + d1 * d1 + d2 * d2), 1e-12f);
    d0 *= inv; d1 *= inv; d2 *= inv;
    float m = -FINF;
    const float* nd = ndir + (size_t)row * K * 3;
    for (int n = 0; n < K; ++n) {
        float th = fmaxf(nd[n * 3] * d0 + nd[n * 3 + 1] * d1 + nd[n * 3 + 2] * d2, 0.f);
        m = fmaxf(m, th);
    }
    fm0[t] = m; // relu(max of relus) == max
}

// ---------------- LDS-tiled GEMM 64x64, BK=32; MODE 0: +bias, MODE 1: bnrelu(conv)+A@W ----------------
// grid: (N/64, M/64); 256 threads: 16x16, each 4 rows x 4 cols.
template <int MODE>
__global__ __launch_bounds__(TPB) void gemm64_kernel(const float* __restrict__ A, const float* __restrict__ W,
                                                     const float* __restrict__ bias,
                                                     const float* __restrict__ conv, const float* __restrict__ stats,
                                                     float* __restrict__ out, int M, int N, int K) {
    __shared__ float As[64][36]; // padded rows (144 B, 16B-aligned)
    __shared__ float Bs[32][68]; // padded rows (272 B, 16B-aligned)
    int t = threadIdx.x;
    int tx = t & 15, ty = t >> 4;
    int colbase = blockIdx.x * 64, rowbase = blockIdx.y * 64;
    int r0 = ty * 4, c0 = tx * 4;
    float4 acc0, acc1, acc2, acc3;
    if (MODE == 0) {
        float4 bv = *(const float4*)(bias + colbase + c0);
        acc0 = bv; acc1 = bv; acc2 = bv; acc3 = bv;
    } else {
        acc0 = make_float4(0.f, 0.f, 0.f, 0.f); acc1 = acc0; acc2 = acc0; acc3 = acc0;
    }
    for (int kt = 0; kt < K; kt += 32) {
#pragma unroll
        for (int l = 0; l < 2; ++l) {
            int lin = t + l * 256;
            int ar = lin >> 3, ak = (lin & 7) << 2;
            *(float4*)&As[ar][ak] = *(const float4*)(A + (size_t)(rowbase + ar) * K + kt + ak);
            int br = lin >> 4, bn = (lin & 15) << 2;
            *(float4*)&Bs[br][bn] = *(const float4*)(W + (size_t)(kt + br) * N + colbase + bn);
        }
        __syncthreads();
#pragma unroll 4
        for (int k = 0; k < 32; ++k) {
            float4 bv = *(const float4*)&Bs[k][c0];
            float a0 = As[r0][k], a1 = As[r0 + 1][k], a2 = As[r0 + 2][k], a3 = As[r0 + 3][k];
            acc0.x += a0 * bv.x; acc0.y += a0 * bv.y; acc0.z += a0 * bv.z; acc0.w += a0 * bv.w;
            acc1.x += a1 * bv.x; acc1.y += a1 * bv.y; acc1.z += a1 * bv.z; acc1.w += a1 * bv.w;
            acc2.x += a2 * bv.x; acc2.y += a2 * bv.y; acc2.z += a2 * bv.z; acc2.w += a2 * bv.w;
            acc3.x += a3 * bv.x; acc3.y += a3 * bv.y; acc3.z += a3 * bv.z; acc3.w += a3 * bv.w;
        }
        __syncthreads();
    }
    float4 accs[4] = {acc0, acc1, acc2, acc3};
    if (MODE == 1) {
        float4 mean = *(const float4*)(stats + colbase + c0);
        float4 inv = *(const float4*)(stats + N + colbase + c0);
#pragma unroll
        for (int rr = 0; rr < 4; ++rr) {
            float4 cv = *(const float4*)(conv + (size_t)(rowbase + r0 + rr) * N + colbase + c0);
            accs[rr].x += fmaxf((cv.x - mean.x) * inv.x, 0.f);
            accs[rr].y += fmaxf((cv.y - mean.y) * inv.y, 0.f);
            accs[rr].z += fmaxf((cv.z - mean.z) * inv.z, 0.f);
            accs[rr].w += fmaxf((cv.w - mean.w) * inv.w, 0.f);
        }
    }
#pragma unroll
    for (int rr = 0; rr < 4; ++rr)
        *(float4*)(out + (size_t)(rowbase + r0 + rr) * N + colbase + c0) = accs[rr];
}

// ---------------- conv_layer: center + max_n(theta * support) ----------------
__global__ __launch_bounds__(TPB) void conv_act_kernel(const float* __restrict__ ndir, const int* __restrict__ knn,
                                const float* __restrict__ fout, const float* __restrict__ dir,
                                float* __restrict__ out, int B, int Vst, int K, int Cout) {
    int t = blockIdx.x * blockDim.x + threadIdx.x;
    if (t >= B * Vst * Cout) return;
    int row = t / Cout, c = t % Cout;
    int b = row / Vst;
    float d0 = dir[c], d1 = dir[Cout + c], d2 = dir[2 * Cout + c];
    float inv = 1.f / fmaxf(sqrtf(d0 * d0 + d1 * d1 + d2 * d2), 1e-12f);
    d0 *= inv; d1 *= inv; d2 *= inv;
    int Cw = 2 * Cout;
    float m = -FINF;
    const float* nd = ndir + (size_t)row * K * 3;
    const int* kr = knn + (size_t)row * K;
    for (int n = 0; n < K; ++n) {
        int j = kr[n];
        float th = fmaxf(nd[n * 3] * d0 + nd[n * 3 + 1] * d1 + nd[n * 3 + 2] * d2, 0.f);
        float s = fout[((size_t)(b * Vst + j)) * Cw + Cout + c];
        m = fmaxf(m, th * s);
    }
    out[t] = fout[(size_t)row * Cw + c] + m;
}

// ---------------- BN stats, two-pass: coalesced float partials + double combine ----------------
__global__ __launch_bounds__(TPB) void bn_partial_kernel(const float* __restrict__ x, float* __restrict__ partial,
                                                         int rows, int C, int nsplit) {
    int t = blockIdx.x * blockDim.x + threadIdx.x;
    if (t >= C * nsplit) return;
    int c = t % C, sp = t / C;
    int chunk = rows / nsplit;
    int r0 = sp * chunk;
    float s = 0.f, ss = 0.f;
    for (int r = r0; r < r0 + chunk; ++r) {
        float v = x[(size_t)r * C + c];
        s += v; ss += v * v;
    }
    partial[(size_t)sp * 2 * C + c] = s;
    partial[(size_t)sp * 2 * C + C + c] = ss;
}

__global__ __launch_bounds__(TPB) void bn_finalize_kernel(const float* __restrict__ partial, float* __restrict__ stats,
                                                          int rows, int C, int nsplit) {
    int c = blockIdx.x * blockDim.x + threadIdx.x;
    if (c >= C) return;
    double s = 0.0, ss = 0.0;
    for (int sp = 0; sp < nsplit; ++sp) {
        s += partial[(size_t)sp * 2 * C + c];
        ss += partial[(size_t)sp * 2 * C + C + c];
    }
    double m = s / rows;
    double var = ss / rows - m * m;
    if (var < 0) var = 0;
    stats[c] = (float)m;
    stats[C + c] = rsqrtf((float)var + 1e-5f);
}

// ---------------- pool: max over 4 NN features, first pn rows ----------------
__global__ __launch_bounds__(TPB) void pool_max_kernel(const float* __restrict__ fm, const int* __restrict__ knn4,
                                float* __restrict__ out, int B, int Vin, int pn, int C) {
    int t = blockIdx.x * blockDim.x + threadIdx.x;
    if (t >= B * pn * C) return;
    int row = t / C, c = t % C;
    int b = row / pn;
    const int* kr = knn4 + (size_t)row * 4;
    float m = -FINF;
    for (int n = 0; n < 4; ++n) {
        int j = kr[n];
        m = fmaxf(m, fm[((size_t)(b * Vin + j)) * C + c]);
    }
    out[t] = m;
}

// ---------------- g = max over vertices ----------------
__global__ __launch_bounds__(TPB) void rowmax_kernel(const float* __restrict__ fm, float* __restrict__ g,
                              int B, int V, int C) {
    int t = blockIdx.x * blockDim.x + threadIdx.x;
    if (t >= B * C) return;
    int b = t / C, c = t % C;
    float m = -FINF;
    for (int i = 0; i < V; ++i) m = fmaxf(m, fm[((size_t)(b * V + i)) * C + c]);
    g[t] = m;
}

// ---------------- wave-per-output: out[r,c] = in[r,:]@w[c,:] + bias[c] ----------------
__global__ __launch_bounds__(TPB, 1) void gemm_t_wave_kernel(const float* __restrict__ in, const float* __restrict__ w,
                                   const float* __restrict__ bias, float* __restrict__ out,
                                   int rows, int Cin, int Cout) {
    int wid = (blockIdx.x * blockDim.x + threadIdx.x) >> 6;
    int lane = threadIdx.x & 63;
    if (wid >= rows * Cout) return;
    int r = wid / Cout, c = wid % Cout;
    const float4* a = (const float4*)(in + (size_t)r * Cin);
    const float4* wr = (const float4*)(w + (size_t)c * Cin);
    int n4 = Cin >> 2;
    float acc = 0.f;
    for (int k = lane; k < n4; k += 64) {
        float4 av = a[k], wv = wr[k];
        acc += av.x * wv.x + av.y * wv.y + av.z * wv.z + av.w * wv.w;
    }
#pragma unroll
    for (int off = 32; off > 0; off >>= 1) acc += __shfl_xor(acc, off, 64);
    if (lane == 0) out[wid] = acc + bias[c];
}

// ---------------- classifier BN stats over batch (32) ----------------
__global__ __launch_bounds__(TPB) void cls_bn_stats_kernel(const float* __restrict__ h, float* __restrict__ stats) {
    int c = blockIdx.x * blockDim.x + threadIdx.x;
    if (c >= 256) return;
    float s = 0.f, ss = 0.f;
    for (int b = 0; b < 32; ++b) {
        float v = h[(size_t)b * 256 + c];
        s += v; ss += v * v;
    }
    float m = s / 32.f;
    float var = ss / 32.f - m * m;
    if (var < 0.f) var = 0.f;
    stats[c] = m;
    stats[256 + c] = rsqrtf(var + 1e-5f);
}

// ---------------- final: wave-per-output relu(bn(h)*g+beta) @ w2^T + b2 ----------------
__global__ __launch_bounds__(TPB, 1) void cls_final_wave_kernel(const float* __restrict__ h, const float* __restrict__ stats,
                                 const float* __restrict__ gam, const float* __restrict__ beta,
                                 const float* __restrict__ w2, const float* __restrict__ b2,
                                 float* __restrict__ out) {
    int wid = (blockIdx.x * blockDim.x + threadIdx.x) >> 6;
    int lane = threadIdx.x & 63;
    if (wid >= 32 * 40) return;
    int b = wid / 40, o = wid % 40;
    float acc = 0.f;
#pragma unroll
    for (int kk = 0; kk < 4; ++kk) {
        int c = lane + kk * 64;
        float v = fmaxf((h[b * 256 + c] - stats[c]) * stats[256 + c] * gam[c] + beta[c], 0.f);
        acc += v * w2[o * 256 + c];
    }
#pragma unroll
    for (int off = 32; off > 0; off >>= 1) acc += __shfl_xor(acc, off, 64);
    if (lane == 0) out[wid] = acc + b2[o];
}

extern "C" void kernel_launch(void* const* d_in, const int* in_sizes, int n_in,
                              void* d_out, int out_size, void* d_ws, size_t ws_size,
                              hipStream_t stream) {
    const float* vertices = (const float*)d_in[0];
    const float* c0_dir = (const float*)d_in[1];
    const float* c1_w  = (const float*)d_in[2];
    const float* c1_b  = (const float*)d_in[3];
    const float* c1_dir = (const float*)d_in[4];
    const float* d1_w  = (const float*)d_in[5];
    const float* c2_w  = (const float*)d_in[6];
    const float* c2_b  = (const float*)d_in[7];
    const float* c2_dir = (const float*)d_in[8];
    const float* d2_w  = (const float*)d_in[9];
    const float* c3_w  = (const float*)d_in[10];
    const float* c3_b  = (const float*)d_in[11];
    const float* c3_dir = (const float*)d_in[12];
    const float* d3_w  = (const float*)d_in[13];
    const float* c4_w  = (const float*)d_in[14];
    const float* c4_b  = (const float*)d_in[15];
    const float* c4_dir = (const float*)d_in[16];
    const float* d4_w  = (const float*)d_in[17];
    const float* cls_w1 = (const float*)d_in[18];
    const float* cls_b1 = (const float*)d_in[19];
    const float* cls_g  = (const float*)d_in[20];
    const float* cls_beta = (const float*)d_in[21];
    const float* cls_w2 = (const float*)d_in[22];
    const float* cls_b2 = (const float*)d_in[23];

    const int B = 32;
    float* ws = (float*)d_ws;
    size_t off = 0;
    auto alloc = [&](size_t n) { float* p = ws + off; off += n; return p; };
    float* verts = alloc(98304);            // B*1024*3
    int*   knn   = (int*)alloc(655360);     // max B*1024*20
    float* ndir  = alloc(1966080);          // max B*1024*20*3
    float* fm0   = alloc(1048576);          // B*1024*32
    float* fm1   = alloc(2097152);          // B*1024*64
    float* fm1p  = alloc(524288);           // B*256*64
    float* fm2   = alloc(1048576);          // B*256*128
    float* fm3   = alloc(2097152);          // B*256*256
    float* fm3p  = alloc(524288);           // B*64*256
    float* fm4   = alloc(2097152);          // B*64*1024
    float* fout  = alloc(4194304);          // max B*1024*128 / B*256*512 / B*64*2048
    float* convp = alloc(2097152);          // pre-BN conv out
    float* stats = alloc(2048);             // mean + inv, max C=1024
    float* gbuf  = alloc(32768);            // B*1024
    float* hbuf  = alloc(8192);             // B*256
    float* hstats = alloc(512);
    float* d1t   = alloc(2048);             // 32 x 64   (d1_w^T: Cin x C)
    float* d2t   = alloc(8192);             // 64 x 128
    float* d3t   = alloc(32768);            // 128 x 256
    float* d4t   = alloc(262144);           // 256 x 1024
    float* partial = alloc(65536);          // bn partials, max 2*C*nsplit

    // ---- weight transposes (input-only deps), fused ----
    transpose_all_kernel<<<nblk(2048 + 8192 + 32768 + 262144), TPB, 0, stream>>>(
        d1_w, d2_w, d3_w, d4_w, d1t, d2t, d3t, d4t);

    // ---- stage 1 (V=1024) ----
    transpose_verts<<<nblk(B * 1024), TPB, 0, stream>>>(vertices, verts, B, 1024);
    knn_radix_kernel<20, 16, true><<<dim3(256, B), TPB, 0, stream>>>(verts, knn, ndir, 1024);
    conv_surface_kernel<<<nblk((long)B * 1024 * 32), TPB, 0, stream>>>(ndir, c0_dir, fm0, B * 1024, 20, 32);
    gemm64_kernel<0><<<dim3(2, 512), TPB, 0, stream>>>(fm0, c1_w, c1_b, nullptr, nullptr, fout, B * 1024, 128, 32);
    conv_act_kernel<<<nblk((long)B * 1024 * 64), TPB, 0, stream>>>(ndir, knn, fout, c1_dir, convp, B, 1024, 20, 64);
    bn_partial_kernel<<<nblk(64 * 256), TPB, 0, stream>>>(convp, partial, B * 1024, 64, 256);
    bn_finalize_kernel<<<nblk(64), TPB, 0, stream>>>(partial, stats, B * 1024, 64, 256);
    gemm64_kernel<1><<<dim3(1, 512), TPB, 0, stream>>>(fm0, d1t, nullptr, convp, stats, fm1, B * 1024, 64, 32);
    // pool 1024 -> 256
    knn_radix_kernel<4, 16, false><<<dim3(64, B), TPB, 0, stream>>>(verts, knn, nullptr, 256);
    pool_max_kernel<<<nblk((long)B * 256 * 64), TPB, 0, stream>>>(fm1, knn, fm1p, B, 1024, 256, 64);

    // ---- stage 2 (V=256) ----
    knn_radix_kernel<20, 4, true><<<dim3(64, B), TPB, 0, stream>>>(verts, knn, ndir, 256);
    gemm64_kernel<0><<<dim3(4, 128), TPB, 0, stream>>>(fm1p, c2_w, c2_b, nullptr, nullptr, fout, B * 256, 256, 64);
    conv_act_kernel<<<nblk((long)B * 256 * 128), TPB, 0, stream>>>(ndir, knn, fout, c2_dir, convp, B, 256, 20, 128);
    bn_partial_kernel<<<nblk(128 * 128), TPB, 0, stream>>>(convp, partial, B * 256, 128, 128);
    bn_finalize_kernel<<<nblk(128), TPB, 0, stream>>>(partial, stats, B * 256, 128, 128);
    gemm64_kernel<1><<<dim3(2, 128), TPB, 0, stream>>>(fm1p, d2t, nullptr, convp, stats, fm2, B * 256, 128, 64);
    gemm64_kernel<0><<<dim3(8, 128), TPB, 0, stream>>>(fm2, c3_w, c3_b, nullptr, nullptr, fout, B * 256, 512, 128);
    conv_act_kernel<<<nblk((long)B * 256 * 256), TPB, 0, stream>>>(ndir, knn, fout, c3_dir, convp, B, 256, 20, 256);
    bn_partial_kernel<<<nblk(256 * 128), TPB, 0, stream>>>(convp, partial, B * 256, 256, 128);
    bn_finalize_kernel<<<nblk(256), TPB, 0, stream>>>(partial, stats, B * 256, 256, 128);
    gemm64_kernel<1><<<dim3(4, 128), TPB, 0, stream>>>(fm2, d3t, nullptr, convp, stats, fm3, B * 256, 256, 128);
    // pool 256 -> 64
    knn_radix_kernel<4, 4, false><<<dim3(16, B), TPB, 0, stream>>>(verts, knn, nullptr, 64);
    pool_max_kernel<<<nblk((long)B * 64 * 256), TPB, 0, stream>>>(fm3, knn, fm3p, B, 256, 64, 256);

    // ---- stage 3 (V=64) ----
    knn_radix_kernel<20, 1, true><<<dim3(16, B), TPB, 0, stream>>>(verts, knn, ndir, 64);
    gemm64_kernel<0><<<dim3(32, 32), TPB, 0, stream>>>(fm3p, c4_w, c4_b, nullptr, nullptr, fout, B * 64, 2048, 256);
    conv_act_kernel<<<nblk((long)B * 64 * 1024), TPB, 0, stream>>>(ndir, knn, fout, c4_dir, convp, B, 64, 20, 1024);
    bn_partial_kernel<<<nblk(1024 * 32), TPB, 0, stream>>>(convp, partial, B * 64, 1024, 32);
    bn_finalize_kernel<<<nblk(1024), TPB, 0, stream>>>(partial, stats, B * 64, 1024, 32);
    gemm64_kernel<1><<<dim3(16, 32), TPB, 0, stream>>>(fm3p, d4t, nullptr, convp, stats, fm4, B * 64, 1024, 256);

    // ---- classifier ----
    rowmax_kernel<<<nblk((long)B * 1024), TPB, 0, stream>>>(fm4, gbuf, B, 64, 1024);
    gemm_t_wave_kernel<<<nblk((long)32 * 256 * 64), TPB, 0, stream>>>(gbuf, cls_w1, cls_b1, hbuf, 32, 1024, 256);
    cls_bn_stats_kernel<<<1, TPB, 0, stream>>>(hbuf, hstats);
    cls_final_wave_kernel<<<nblk((long)32 * 40 * 64), TPB, 0, stream>>>(hbuf, hstats, cls_g, cls_beta, cls_w2, cls_b2, (float*)d_out);
}

// Round 8
// 681.486 us; speedup vs baseline: 78.3181x; 1.0431x over previous
//
#include <hip/hip_runtime.h>

#define TPB 256
static inline int nblk(long n) { return (int)((n + TPB - 1) / TPB); }

#define FINF 3.402823466e38f

// ---------------- fused input transposes: verts (B,3,V)->(B,V,3) + d1..d4 w^T ----------------
__global__ __launch_bounds__(TPB) void transpose_all_kernel(const float* __restrict__ vin, float* __restrict__ verts,
                                                            const float* __restrict__ d1, const float* __restrict__ d2,
                                                            const float* __restrict__ d3, const float* __restrict__ d4,
                                                            float* __restrict__ o1, float* __restrict__ o2,
                                                            float* __restrict__ o3, float* __restrict__ o4) {
    int t = blockIdx.x * blockDim.x + threadIdx.x;
    if (t < 32768) { // verts: B=32, V=1024
        int b = t >> 10, i = t & 1023;
        const float* p = vin + (size_t)b * 3072;
        float* o = verts + (size_t)t * 3;
        o[0] = p[i]; o[1] = p[1024 + i]; o[2] = p[2048 + i];
        return;
    }
    int t1 = t - 32768;
    if (t1 < 2048) { int r = t1 / 32, c = t1 % 32; o1[c * 64 + r] = d1[t1]; return; }
    int t2 = t1 - 2048;
    if (t2 < 8192) { int r = t2 / 64, c = t2 % 64; o2[c * 128 + r] = d2[t2]; return; }
    int t3 = t2 - 8192;
    if (t3 < 32768) { int r = t3 / 128, c = t3 % 128; o3[c * 256 + r] = d3[t3]; return; }
    int t4 = t3 - 32768;
    if (t4 < 262144) { int r = t4 / 256, c = t4 % 256; o4[c * 1024 + r] = d4[t4]; }
}

// ---------------- KNN radix-select, fused epilogues ----------------
// Wave-per-vertex. Exact K-th smallest via binary search on float bit patterns
// (ballot counting). Initial hi: pair-min bound - 32 disjoint lane-pair mins,
// wave-max M has >=32 candidates <= M, valid upper bound for K<=20.
// WDIR: write normalized neighbor dirs. CSURF: also compute conv_surface fm0.
// POOL: max-pool features over the 4 NN (no knn/ndir global writes).
template <int K, int NS, bool WDIR, bool CSURF, bool POOL>
__global__ __launch_bounds__(TPB, 1) void knn_radix_kernel(const float* __restrict__ verts,
                                                           int* __restrict__ knn, float* __restrict__ ndir,
                                                           int V_out, const float* __restrict__ c0dir,
                                                           float* __restrict__ fm0,
                                                           const float* __restrict__ fmin, float* __restrict__ pooled,
                                                           int C, int Vin) {
    constexpr int VF = NS * 64;
    __shared__ float4 pts[VF]; // (x, y, z, |p|^2)
    __shared__ int sidx[4][K];
    __shared__ float sdir[4][K][3];
    int b = blockIdx.y;
    const float* vb = verts + (size_t)b * 1024 * 3;
    for (int j = threadIdx.x; j < VF; j += blockDim.x) {
        float x = vb[j * 3], y = vb[j * 3 + 1], z = vb[j * 3 + 2];
        pts[j] = make_float4(x, y, z, x * x + y * y + z * z);
    }
    __syncthreads();
    int lane = threadIdx.x & 63;
    int w = threadIdx.x >> 6;
    int i = blockIdx.x * 4 + w; // 4 waves/block, grid sized exactly
    if (i >= V_out) return;
    float4 pi = pts[i];
    unsigned ud[NS];
    unsigned lmin = 0xFFFFFFFFu;
#pragma unroll
    for (int s = 0; s < NS; ++s) {
        int j = s * 64 + lane;
        float4 pj = pts[j];
        float dist = pi.w + pj.w - 2.f * (pi.x * pj.x + pi.y * pj.y + pi.z * pj.z);
        dist = fmaxf(dist, 0.f); // keep bit-monotone (fp rounding can go < 0)
        unsigned v = (j == i) ? 0xFFFFFFFFu : __float_as_uint(dist);
        ud[s] = v;
        lmin = v < lmin ? v : lmin;
    }
    // pair-min upper bound: 32 disjoint pairs of lane-mins; every pair-min is a
    // real candidate (only one self slot per wave), so >=32 candidates <= M.
    unsigned pmin = lmin;
    {
        unsigned o = (unsigned)__shfl_xor((int)pmin, 1, 64);
        pmin = o < pmin ? o : pmin;
    }
    unsigned gmin = lmin, M = pmin;
#pragma unroll
    for (int off = 32; off > 1; off >>= 1) {
        unsigned on = (unsigned)__shfl_xor((int)gmin, off, 64);
        gmin = on < gmin ? on : gmin;
        unsigned om = (unsigned)__shfl_xor((int)M, off, 64);
        M = om > M ? om : M;
    }
    {
        unsigned on = (unsigned)__shfl_xor((int)gmin, 1, 64);
        gmin = on < gmin ? on : gmin;
    }
    // invariant: count(lo) < K <= count(hi); count(m) = #{ud < m}
    unsigned lo = gmin, hi = M + 1u;
    while (hi - lo > 1u) {
        unsigned mid = lo + ((hi - lo) >> 1);
        int cnt = 0;
#pragma unroll
        for (int s = 0; s < NS; ++s)
            cnt += __popcll(__ballot(ud[s] < mid));
        if (cnt >= K) hi = mid; else lo = mid;
    }
    unsigned T = lo;
    int* orow = POOL ? nullptr : (knn + ((size_t)(b * V_out + i)) * K);
    unsigned long long lmask = (1ull << lane) - 1ull;
    int base = 0;
#pragma unroll
    for (int s = 0; s < NS; ++s) {
        unsigned long long m = __ballot(ud[s] < T);
        if (ud[s] < T) {
            int p = base + __popcll(m & lmask);
            sidx[w][p] = s * 64 + lane;
            if (!POOL) orow[p] = s * 64 + lane;
        }
        base += __popcll(m);
    }
    int need = K - base; // >= 1 ties at T fill the rest, lowest index first
    int run = 0;
#pragma unroll
    for (int s = 0; s < NS; ++s) {
        unsigned long long m = __ballot(ud[s] == T);
        int r = run + __popcll(m & lmask);
        if (ud[s] == T && r < need) {
            sidx[w][base + r] = s * 64 + lane;
            if (!POOL) orow[base + r] = s * 64 + lane;
        }
        run += __popcll(m);
    }
    // --- epilogues: wave-synchronous LDS reads (same wave wrote sidx[w]) ---
    if (WDIR) {
        if (lane < K) {
            int j = sidx[w][lane];
            float4 pj = pts[j];
            float dx = pj.x - pi.x, dy = pj.y - pi.y, dz = pj.z - pi.z;
            float inv = 1.f / fmaxf(sqrtf(dx * dx + dy * dy + dz * dz), 1e-12f);
            float* o = ndir + ((size_t)(b * V_out + i) * K + lane) * 3;
            float nx = dx * inv, ny = dy * inv, nz = dz * inv;
            o[0] = nx; o[1] = ny; o[2] = nz;
            if (CSURF) { sdir[w][lane][0] = nx; sdir[w][lane][1] = ny; sdir[w][lane][2] = nz; }
        }
        if (CSURF && lane < 32) {
            int c = lane;
            float d0 = c0dir[c], d1 = c0dir[32 + c], d2 = c0dir[64 + c];
            float inv = 1.f / fmaxf(sqrtf(d0 * d0 + d1 * d1 + d2 * d2), 1e-12f);
            d0 *= inv; d1 *= inv; d2 *= inv;
            float m = 0.f;
            for (int n = 0; n < K; ++n) {
                float th = sdir[w][n][0] * d0 + sdir[w][n][1] * d1 + sdir[w][n][2] * d2;
                m = fmaxf(m, th);
            }
            fm0[(size_t)(b * V_out + i) * 32 + c] = m; // relu(max) == max of relus
        }
    }
    if (POOL) {
        int j0 = sidx[w][0], j1 = sidx[w][1], j2 = sidx[w][2], j3 = sidx[w][3];
        const float* fb = fmin + (size_t)b * Vin * C;
        float* ob = pooled + ((size_t)(b * V_out + i)) * C;
        for (int c = lane; c < C; c += 64) {
            float m = fmaxf(fmaxf(fb[(size_t)j0 * C + c], fb[(size_t)j1 * C + c]),
                            fmaxf(fb[(size_t)j2 * C + c], fb[(size_t)j3 * C + c]));
            ob[c] = m;
        }
    }
}

// ---------------- LDS-tiled GEMM 64x64, BK=32 ----------------
// MODE 0: out = A@W + bias.  MODE 1: out = bnrelu(conv) + A@W, with BN stats
// finalized in-kernel from the partial buffer (mean/rsqrt per column slice).
template <int MODE>
__global__ __launch_bounds__(TPB) void gemm64_kernel(const float* __restrict__ A, const float* __restrict__ W,
                                                     const float* __restrict__ bias,
                                                     const float* __restrict__ conv, const float* __restrict__ partial,
                                                     float* __restrict__ out, int M, int N, int K, int nsplit) {
    __shared__ float As[64][36]; // padded rows (144 B, 16B-aligned)
    __shared__ float Bs[32][68]; // padded rows (272 B, 16B-aligned)
    __shared__ float smean[64], sinv[64];
    int t = threadIdx.x;
    int tx = t & 15, ty = t >> 4;
    int colbase = blockIdx.x * 64, rowbase = blockIdx.y * 64;
    int r0 = ty * 4, c0 = tx * 4;
    if (MODE == 1 && t < 64) {
        int c = colbase + t;
        double s = 0.0, ss = 0.0;
        for (int sp = 0; sp < nsplit; ++sp) {
            s += partial[(size_t)sp * 2 * N + c];
            ss += partial[(size_t)sp * 2 * N + N + c];
        }
        double mean = s / M;
        double var = ss / M - mean * mean;
        if (var < 0) var = 0;
        smean[t] = (float)mean;
        sinv[t] = rsqrtf((float)var + 1e-5f);
    }
    float4 acc0, acc1, acc2, acc3;
    if (MODE == 0) {
        float4 bv = *(const float4*)(bias + colbase + c0);
        acc0 = bv; acc1 = bv; acc2 = bv; acc3 = bv;
    } else {
        acc0 = make_float4(0.f, 0.f, 0.f, 0.f); acc1 = acc0; acc2 = acc0; acc3 = acc0;
    }
    for (int kt = 0; kt < K; kt += 32) {
#pragma unroll
        for (int l = 0; l < 2; ++l) {
            int lin = t + l * 256;
            int ar = lin >> 3, ak = (lin & 7) << 2;
            *(float4*)&As[ar][ak] = *(const float4*)(A + (size_t)(rowbase + ar) * K + kt + ak);
            int br = lin >> 4, bn = (lin & 15) << 2;
            *(float4*)&Bs[br][bn] = *(const float4*)(W + (size_t)(kt + br) * N + colbase + bn);
        }
        __syncthreads();
#pragma unroll 4
        for (int k = 0; k < 32; ++k) {
            float4 bv = *(const float4*)&Bs[k][c0];
            float a0 = As[r0][k], a1 = As[r0 + 1][k], a2 = As[r0 + 2][k], a3 = As[r0 + 3][k];
            acc0.x += a0 * bv.x; acc0.y += a0 * bv.y; acc0.z += a0 * bv.z; acc0.w += a0 * bv.w;
            acc1.x += a1 * bv.x; acc1.y += a1 * bv.y; acc1.z += a1 * bv.z; acc1.w += a1 * bv.w;
            acc2.x += a2 * bv.x; acc2.y += a2 * bv.y; acc2.z += a2 * bv.z; acc2.w += a2 * bv.w;
            acc3.x += a3 * bv.x; acc3.y += a3 * bv.y; acc3.z += a3 * bv.z; acc3.w += a3 * bv.w;
        }
        __syncthreads();
    }
    float4 accs[4] = {acc0, acc1, acc2, acc3};
    if (MODE == 1) {
        float4 mean = *(const float4*)&smean[c0];
        float4 inv = *(const float4*)&sinv[c0];
#pragma unroll
        for (int rr = 0; rr < 4; ++rr) {
            float4 cv = *(const float4*)(conv + (size_t)(rowbase + r0 + rr) * N + colbase + c0);
            accs[rr].x += fmaxf((cv.x - mean.x) * inv.x, 0.f);
            accs[rr].y += fmaxf((cv.y - mean.y) * inv.y, 0.f);
            accs[rr].z += fmaxf((cv.z - mean.z) * inv.z, 0.f);
            accs[rr].w += fmaxf((cv.w - mean.w) * inv.w, 0.f);
        }
    }
#pragma unroll
    for (int rr = 0; rr < 4; ++rr)
        *(float4*)(out + (size_t)(rowbase + r0 + rr) * N + colbase + c0) = accs[rr];
}

// ---------------- conv_layer: center + max_n(theta * support) ----------------
__global__ __launch_bounds__(TPB) void conv_act_kernel(const float* __restrict__ ndir, const int* __restrict__ knn,
                                const float* __restrict__ fout, const float* __restrict__ dir,
                                float* __restrict__ out, int B, int Vst, int K, int Cout) {
    int t = blockIdx.x * blockDim.x + threadIdx.x;
    if (t >= B * Vst * Cout) return;
    int row = t / Cout, c = t % Cout;
    int b = row / Vst;
    float d0 = dir[c], d1 = dir[Cout + c], d2 = dir[2 * Cout + c];
    float inv = 1.f / fmaxf(sqrtf(d0 * d0 + d1 * d1 + d2 * d2), 1e-12f);
    d0 *= inv; d1 *= inv; d2 *= inv;
    int Cw = 2 * Cout;
    float m = -FINF;
    const float* nd = ndir + (size_t)row * K * 3;
    const int* kr = knn + (size_t)row * K;
    for (int n = 0; n < K; ++n) {
        int j = kr[n];
        float th = fmaxf(nd[n * 3] * d0 + nd[n * 3 + 1] * d1 + nd[n * 3 + 2] * d2, 0.f);
        float s = fout[((size_t)(b * Vst + j)) * Cw + Cout + c];
        m = fmaxf(m, th * s);
    }
    out[t] = fout[(size_t)row * Cw + c] + m;
}

// ---------------- BN stats pass 1: coalesced float partials ----------------
__global__ __launch_bounds__(TPB) void bn_partial_kernel(const float* __restrict__ x, float* __restrict__ partial,
                                                         int rows, int C, int nsplit) {
    int t = blockIdx.x * blockDim.x + threadIdx.x;
    if (t >= C * nsplit) return;
    int c = t % C, sp = t / C;
    int chunk = rows / nsplit;
    int r0 = sp * chunk;
    float s = 0.f, ss = 0.f;
    for (int r = r0; r < r0 + chunk; ++r) {
        float v = x[(size_t)r * C + c];
        s += v; ss += v * v;
    }
    partial[(size_t)sp * 2 * C + c] = s;
    partial[(size_t)sp * 2 * C + C + c] = ss;
}

// ---------------- g = max over vertices ----------------
__global__ __launch_bounds__(TPB) void rowmax_kernel(const float* __restrict__ fm, float* __restrict__ g,
                              int B, int V, int C) {
    int t = blockIdx.x * blockDim.x + threadIdx.x;
    if (t >= B * C) return;
    int b = t / C, c = t % C;
    float m = -FINF;
    for (int i = 0; i < V; ++i) m = fmaxf(m, fm[((size_t)(b * V + i)) * C + c]);
    g[t] = m;
}

// ---------------- wave-per-output: out[r,c] = in[r,:]@w[c,:] + bias[c] ----------------
__global__ __launch_bounds__(TPB, 1) void gemm_t_wave_kernel(const float* __restrict__ in, const float* __restrict__ w,
                                   const float* __restrict__ bias, float* __restrict__ out,
                                   int rows, int Cin, int Cout) {
    int wid = (blockIdx.x * blockDim.x + threadIdx.x) >> 6;
    int lane = threadIdx.x & 63;
    if (wid >= rows * Cout) return;
    int r = wid / Cout, c = wid % Cout;
    const float4* a = (const float4*)(in + (size_t)r * Cin);
    const float4* wr = (const float4*)(w + (size_t)c * Cin);
    int n4 = Cin >> 2;
    float acc = 0.f;
    for (int k = lane; k < n4; k += 64) {
        float4 av = a[k], wv = wr[k];
        acc += av.x * wv.x + av.y * wv.y + av.z * wv.z + av.w * wv.w;
    }
#pragma unroll
    for (int off = 32; off > 0; off >>= 1) acc += __shfl_xor(acc, off, 64);
    if (lane == 0) out[wid] = acc + bias[c];
}

// ---------------- classifier BN stats over batch (32) ----------------
__global__ __launch_bounds__(TPB) void cls_bn_stats_kernel(const float* __restrict__ h, float* __restrict__ stats) {
    int c = blockIdx.x * blockDim.x + threadIdx.x;
    if (c >= 256) return;
    float s = 0.f, ss = 0.f;
    for (int b = 0; b < 32; ++b) {
        float v = h[(size_t)b * 256 + c];
        s += v; ss += v * v;
    }
    float m = s / 32.f;
    float var = ss / 32.f - m * m;
    if (var < 0.f) var = 0.f;
    stats[c] = m;
    stats[256 + c] = rsqrtf(var + 1e-5f);
}

// ---------------- final: wave-per-output relu(bn(h)*g+beta) @ w2^T + b2 ----------------
__global__ __launch_bounds__(TPB, 1) void cls_final_wave_kernel(const float* __restrict__ h, const float* __restrict__ stats,
                                 const float* __restrict__ gam, const float* __restrict__ beta,
                                 const float* __restrict__ w2, const float* __restrict__ b2,
                                 float* __restrict__ out) {
    int wid = (blockIdx.x * blockDim.x + threadIdx.x) >> 6;
    int lane = threadIdx.x & 63;
    if (wid >= 32 * 40) return;
    int b = wid / 40, o = wid % 40;
    float acc = 0.f;
#pragma unroll
    for (int kk = 0; kk < 4; ++kk) {
        int c = lane + kk * 64;
        float v = fmaxf((h[b * 256 + c] - stats[c]) * stats[256 + c] * gam[c] + beta[c], 0.f);
        acc += v * w2[o * 256 + c];
    }
#pragma unroll
    for (int off = 32; off > 0; off >>= 1) acc += __shfl_xor(acc, off, 64);
    if (lane == 0) out[wid] = acc + b2[o];
}

extern "C" void kernel_launch(void* const* d_in, const int* in_sizes, int n_in,
                              void* d_out, int out_size, void* d_ws, size_t ws_size,
                              hipStream_t stream) {
    const float* vertices = (const float*)d_in[0];
    const float* c0_dir = (const float*)d_in[1];
    const float* c1_w  = (const float*)d_in[2];
    const float* c1_b  = (const float*)d_in[3];
    const float* c1_dir = (const float*)d_in[4];
    const float* d1_w  = (const float*)d_in[5];
    const float* c2_w  = (const float*)d_in[6];
    const float* c2_b  = (const float*)d_in[7];
    const float* c2_dir = (const float*)d_in[8];
    const float* d2_w  = (const float*)d_in[9];
    const float* c3_w  = (const float*)d_in[10];
    const float* c3_b  = (const float*)d_in[11];
    const float* c3_dir = (const float*)d_in[12];
    const float* d3_w  = (const float*)d_in[13];
    const float* c4_w  = (const float*)d_in[14];
    const float* c4_b  = (const float*)d_in[15];
    const float* c4_dir = (const float*)d_in[16];
    const float* d4_w  = (const float*)d_in[17];
    const float* cls_w1 = (const float*)d_in[18];
    const float* cls_b1 = (const float*)d_in[19];
    const float* cls_g  = (const float*)d_in[20];
    const float* cls_beta = (const float*)d_in[21];
    const float* cls_w2 = (const float*)d_in[22];
    const float* cls_b2 = (const float*)d_in[23];

    const int B = 32;
    float* ws = (float*)d_ws;
    size_t off = 0;
    auto alloc = [&](size_t n) { float* p = ws + off; off += n; return p; };
    float* verts = alloc(98304);            // B*1024*3
    int*   knn   = (int*)alloc(655360);     // max B*1024*20
    float* ndir  = alloc(1966080);          // max B*1024*20*3
    float* fm0   = alloc(1048576);          // B*1024*32
    float* fm1   = alloc(2097152);          // B*1024*64
    float* fm1p  = alloc(524288);           // B*256*64
    float* fm2   = alloc(1048576);          // B*256*128
    float* fm3   = alloc(2097152);          // B*256*256
    float* fm3p  = alloc(524288);           // B*64*256
    float* fm4   = alloc(2097152);          // B*64*1024
    float* fout  = alloc(4194304);          // max fout sizes
    float* convp = alloc(2097152);          // pre-BN conv out
    float* gbuf  = alloc(32768);            // B*1024
    float* hbuf  = alloc(8192);             // B*256
    float* hstats = alloc(512);
    float* d1t   = alloc(2048);             // 32 x 64
    float* d2t   = alloc(8192);             // 64 x 128
    float* d3t   = alloc(32768);            // 128 x 256
    float* d4t   = alloc(262144);           // 256 x 1024
    float* partial = alloc(65536);          // bn partials, max 2*C*nsplit

    // ---- fused input transposes ----
    transpose_all_kernel<<<nblk(32768 + 2048 + 8192 + 32768 + 262144), TPB, 0, stream>>>(
        vertices, verts, d1_w, d2_w, d3_w, d4_w, d1t, d2t, d3t, d4t);

    // ---- stage 1 (V=1024) ----
    knn_radix_kernel<20, 16, true, true, false><<<dim3(256, B), TPB, 0, stream>>>(
        verts, knn, ndir, 1024, c0_dir, fm0, nullptr, nullptr, 0, 0);
    gemm64_kernel<0><<<dim3(2, 512), TPB, 0, stream>>>(fm0, c1_w, c1_b, nullptr, nullptr, fout, B * 1024, 128, 32, 0);
    conv_act_kernel<<<nblk((long)B * 1024 * 64), TPB, 0, stream>>>(ndir, knn, fout, c1_dir, convp, B, 1024, 20, 64);
    bn_partial_kernel<<<nblk(64 * 256), TPB, 0, stream>>>(convp, partial, B * 1024, 64, 256);
    gemm64_kernel<1><<<dim3(1, 512), TPB, 0, stream>>>(fm0, d1t, nullptr, convp, partial, fm1, B * 1024, 64, 32, 256);
    // pool 1024 -> 256 (knn4 + max-pool fused)
    knn_radix_kernel<4, 16, false, false, true><<<dim3(64, B), TPB, 0, stream>>>(
        verts, nullptr, nullptr, 256, nullptr, nullptr, fm1, fm1p, 64, 1024);

    // ---- stage 2 (V=256) ----
    knn_radix_kernel<20, 4, true, false, false><<<dim3(64, B), TPB, 0, stream>>>(
        verts, knn, ndir, 256, nullptr, nullptr, nullptr, nullptr, 0, 0);
    gemm64_kernel<0><<<dim3(4, 128), TPB, 0, stream>>>(fm1p, c2_w, c2_b, nullptr, nullptr, fout, B * 256, 256, 64, 0);
    conv_act_kernel<<<nblk((long)B * 256 * 128), TPB, 0, stream>>>(ndir, knn, fout, c2_dir, convp, B, 256, 20, 128);
    bn_partial_kernel<<<nblk(128 * 128), TPB, 0, stream>>>(convp, partial, B * 256, 128, 128);
    gemm64_kernel<1><<<dim3(2, 128), TPB, 0, stream>>>(fm1p, d2t, nullptr, convp, partial, fm2, B * 256, 128, 64, 128);
    gemm64_kernel<0><<<dim3(8, 128), TPB, 0, stream>>>(fm2, c3_w, c3_b, nullptr, nullptr, fout, B * 256, 512, 128, 0);
    conv_act_kernel<<<nblk((long)B * 256 * 256), TPB, 0, stream>>>(ndir, knn, fout, c3_dir, convp, B, 256, 20, 256);
    bn_partial_kernel<<<nblk(256 * 128), TPB, 0, stream>>>(convp, partial, B * 256, 256, 128);
    gemm64_kernel<1><<<dim3(4, 128), TPB, 0, stream>>>(fm2, d3t, nullptr, convp, partial, fm3, B * 256, 256, 128, 128);
    // pool 256 -> 64 (knn4 + max-pool fused)
    knn_radix_kernel<4, 4, false, false, true><<<dim3(16, B), TPB, 0, stream>>>(
        verts, nullptr, nullptr, 64, nullptr, nullptr, fm3, fm3p, 256, 256);

    // ---- stage 3 (V=64) ----
    knn_radix_kernel<20, 1, true, false, false><<<dim3(16, B), TPB, 0, stream>>>(
        verts, knn, ndir, 64, nullptr, nullptr, nullptr, nullptr, 0, 0);
    gemm64_kernel<0><<<dim3(32, 32), TPB, 0, stream>>>(fm3p, c4_w, c4_b, nullptr, nullptr, fout, B * 64, 2048, 256, 0);
    conv_act_kernel<<<nblk((long)B * 64 * 1024), TPB, 0, stream>>>(ndir, knn, fout, c4_dir, convp, B, 64, 20, 1024);
    bn_partial_kernel<<<nblk(1024 * 32), TPB, 0, stream>>>(convp, partial, B * 64, 1024, 32);
    gemm64_kernel<1><<<dim3(16, 32), TPB, 0, stream>>>(fm3p, d4t, nullptr, convp, partial, fm4, B * 64, 1024, 256, 32);

    // ---- classifier ----
    rowmax_kernel<<<nblk((long)B * 1024), TPB, 0, stream>>>(fm4, gbuf, B, 64, 1024);
    gemm_t_wave_kernel<<<nblk((long)32 * 256 * 64), TPB, 0, stream>>>(gbuf, cls_w1, cls_b1, hbuf, 32, 1024, 256);
    cls_bn_stats_kernel<<<1, TPB, 0, stream>>>(hbuf, hstats);
    cls_final_wave_kernel<<<nblk((long)32 * 40 * 64), TPB, 0, stream>>>(hbuf, hstats, cls_g, cls_beta, cls_w2, cls_b2, (float*)d_out);
}